// Round 6
// baseline (7928.680 us; speedup 1.0000x reference)
//
#include <hip/hip_runtime.h>
#include <hip/hip_bf16.h>
#include <stdint.h>

typedef __hip_bfloat16 bf16;
typedef __attribute__((ext_vector_type(4))) float f32x4;
typedef __attribute__((ext_vector_type(8))) short short8v;
typedef __attribute__((ext_vector_type(4))) short short4v;

union U8 { short8v v; bf16 h[8]; };
union U4 { short4v v; bf16 h[4]; };

#define DEV static __device__ __forceinline__

DEV bf16 f2bf(float f) { return __float2bfloat16(f); }
DEV float bf2f(bf16 h) { return __bfloat162float(h); }

DEV void async_copy16(bf16* lds, const bf16* g) {
  __builtin_amdgcn_global_load_lds(
      (const __attribute__((address_space(1))) unsigned int*)g,
      (__attribute__((address_space(3))) unsigned int*)lds,
      16, 0, 0);
}

// ---------------------------------------------------------------- GEMM 256x256
// C(M,N) = act( A(M,K)bf16 @ BT(N,K)^T + bias + Cin ), 8 waves (2Mx4N), BK=32.
// T3 minimum 2-phase: STAGE(next) -> ds_read+MFMA(cur) -> __syncthreads -> swap.
// __syncthreads supplies the vmcnt(0)+barrier drain (safe against reorder hazards);
// overlap comes from issuing next-tile global_load_lds BEFORE the compute phase.
template<bool RELU, bool BIAS, bool ADDC, bool OBF16>
__global__ __launch_bounds__(512)
void gemm256(const bf16* __restrict__ A, const bf16* __restrict__ BT,
             const float* __restrict__ bias, const float* __restrict__ Cin,
             void* __restrict__ Dout, int M, int N, int K)
{
  __shared__ __align__(16) bf16 lds[32768];   // 2 bufs x (A 8192 + B 8192 elems)
  const int tid = threadIdx.x;
  const int m0 = blockIdx.y * 256, n0 = blockIdx.x * 256;
  const int wid = tid >> 6, lane = tid & 63;
  const int wr = wid >> 2, wc = wid & 3;       // 2 x 4 wave grid
  const int r = lane & 15, g = lane >> 4;

  const int srow = tid >> 2;                   // 0..127
  const int scol = (tid & 3) * 8;              // k-elem offset of this thread's 16B
  const bf16* aS0 = A  + (size_t)(m0 + srow) * K + scol;
  const bf16* aS1 = A  + (size_t)(m0 + srow + 128) * K + scol;
  const bf16* bS0 = BT + (size_t)(n0 + srow) * K + scol;
  const bf16* bS1 = BT + (size_t)(n0 + srow + 128) * K + scol;

  const int NT = K >> 5;                       // K-tiles of 32

  f32x4 acc[8][4];
  #pragma unroll
  for (int i = 0; i < 8; ++i)
    #pragma unroll
    for (int j = 0; j < 4; ++j) acc[i][j] = (f32x4){0.f, 0.f, 0.f, 0.f};

  auto STAGE = [&](int t, int buf) {           // 4 vmem ops / thread / tile
    bf16* dst = &lds[buf * 16384];
    const int kt = t << 5;
    async_copy16(dst +          tid * 8, aS0 + kt);
    async_copy16(dst +  4096 +  tid * 8, aS1 + kt);
    async_copy16(dst +  8192 +  tid * 8, bS0 + kt);
    async_copy16(dst + 12288 +  tid * 8, bS1 + kt);
  };

  STAGE(0, 0);
  __syncthreads();                             // tile 0 landed
  int cur = 0;
  for (int t = 0; t < NT; ++t) {
    if (t + 1 < NT) STAGE(t + 1, cur ^ 1);     // issue next tile; in flight during compute

    const bf16* Ab = &lds[cur * 16384];
    const bf16* Bb = Ab + 8192;
    short8v af[8], bfr[4];
    #pragma unroll
    for (int mi = 0; mi < 8; ++mi)
      af[mi] = *(const short8v*)&Ab[(wr*128 + mi*16 + r) * 32 + g*8];
    #pragma unroll
    for (int ni = 0; ni < 4; ++ni)
      bfr[ni] = *(const short8v*)&Bb[(wc*64 + ni*16 + r) * 32 + g*8];

    __builtin_amdgcn_s_setprio(1);
    #pragma unroll
    for (int mi = 0; mi < 8; ++mi)
      #pragma unroll
      for (int ni = 0; ni < 4; ++ni)
        acc[mi][ni] = __builtin_amdgcn_mfma_f32_16x16x32_bf16(af[mi], bfr[ni], acc[mi][ni], 0, 0, 0);
    __builtin_amdgcn_s_setprio(0);

    __syncthreads();                           // drains vmcnt(0): next tile landed; reads done
    cur ^= 1;
  }

  const int mbase = m0 + wr * 128;
  const int nbase = n0 + wc * 64;
  #pragma unroll
  for (int ni = 0; ni < 4; ++ni) {
    const int col = nbase + ni*16 + r;
    const float bv = BIAS ? bias[col] : 0.f;
    #pragma unroll
    for (int mi = 0; mi < 8; ++mi) {
      #pragma unroll
      for (int b4 = 0; b4 < 4; ++b4) {
        const int row = mbase + mi*16 + g*4 + b4;
        float v = acc[mi][ni][b4] + bv;
        if (ADDC) v += Cin[(size_t)row * N + col];
        if (RELU) v = fmaxf(v, 0.f);
        if (OBF16) ((bf16*)Dout)[(size_t)row * N + col] = f2bf(v);
        else       ((float*)Dout)[(size_t)row * N + col] = v;
      }
    }
  }
}

// ---------------------------------------------------------------- weights: W(K,N) f32 -> WT(N,K) bf16 (batched over z)
__global__ __launch_bounds__(256)
void transpose_w(const float* __restrict__ W, bf16* __restrict__ WT, int K, int N,
                 size_t sW, size_t sWT)
{
  const float* Wp = W + (size_t)blockIdx.z * sW;
  bf16* WTp = WT + (size_t)blockIdx.z * sWT;
  __shared__ float tl[32][33];
  const int n0 = blockIdx.x * 32, k0 = blockIdx.y * 32;
  const int r = threadIdx.x >> 5, c = threadIdx.x & 31;
  #pragma unroll
  for (int rr = r; rr < 32; rr += 8) tl[rr][c] = Wp[(size_t)(k0 + rr) * N + n0 + c];
  __syncthreads();
  #pragma unroll
  for (int rr = r; rr < 32; rr += 8) WTp[(size_t)(n0 + rr) * K + k0 + c] = f2bf(tl[c][rr]);
}

// ---------------------------------------------------------------- gather (chunked): X rows [row0, row0+grid)
__global__ __launch_bounds__(256)
void gather_kernel(const int* __restrict__ off_ids, const int* __restrict__ def_ids,
                   const int* __restrict__ off_pos, const int* __restrict__ def_pos,
                   const float* __restrict__ pemb, const float* __restrict__ remb,
                   int row0, bf16* __restrict__ X, int* __restrict__ cbuf)
{
  const int grow = row0 + blockIdx.x;
  const int b = grow / 10, t = grow % 10;
  int pid, pos, role;
  if (t < 5) { pid = off_ids[b*5 + t];   pos = off_pos[b*5 + t];   role = 0; }
  else       { pid = def_ids[b*5 + t-5]; pos = def_pos[b*5 + t-5]; role = 1; }
  const int col = threadIdx.x * 4;       // 0..1020
  const float* src = (col < 512) ? (pemb + (size_t)pid * 512 + col)
                                 : (remb + (size_t)role * 512 + (col - 512));
  f32x4 v = *(const f32x4*)src;
  U4 u;
  u.h[0] = f2bf(v[0]); u.h[1] = f2bf(v[1]); u.h[2] = f2bf(v[2]); u.h[3] = f2bf(v[3]);
  *(short4v*)(X + (size_t)blockIdx.x * 1024 + col) = u.v;
  if (threadIdx.x == 0) cbuf[grow] = role * 5 + pos;
}

// ---------------------------------------------------------------- LayerNorm rows of 512, f32 in -> bf16 out
__global__ __launch_bounds__(256)
void ln_kernel(const float* __restrict__ Zin, const float* __restrict__ gam,
               const float* __restrict__ bet, bf16* __restrict__ outp)
{
  const int w = threadIdx.x >> 6, lane = threadIdx.x & 63;
  const size_t row = (size_t)blockIdx.x * 4 + w;
  const float* zp = Zin + row * 512 + lane * 8;
  f32x4 v0 = *(const f32x4*)zp;
  f32x4 v1 = *(const f32x4*)(zp + 4);
  float s = 0.f, ss = 0.f;
  #pragma unroll
  for (int j = 0; j < 4; ++j) { s += v0[j]; ss += v0[j]*v0[j]; }
  #pragma unroll
  for (int j = 0; j < 4; ++j) { s += v1[j]; ss += v1[j]*v1[j]; }
  for (int d0 = 1; d0 < 64; d0 <<= 1) { s += __shfl_xor(s, d0); ss += __shfl_xor(ss, d0); }
  const float mu = s * (1.f/512.f);
  const float rstd = rsqrtf(ss * (1.f/512.f) - mu*mu + 1e-5f);
  const float* gp = gam + lane * 8;
  const float* bp = bet + lane * 8;
  f32x4 g0 = *(const f32x4*)gp, g1 = *(const f32x4*)(gp + 4);
  f32x4 b0 = *(const f32x4*)bp, b1 = *(const f32x4*)(bp + 4);
  U8 u;
  #pragma unroll
  for (int j = 0; j < 4; ++j) u.h[j]     = f2bf((v0[j]-mu)*rstd*g0[j] + b0[j]);
  #pragma unroll
  for (int j = 0; j < 4; ++j) u.h[4 + j] = f2bf((v1[j]-mu)*rstd*g1[j] + b1[j]);
  *(short8v*)(outp + row * 512 + lane * 8) = u.v;
}

// ---------------------------------------------------------------- attention: one wave per (local b, h)
__global__ __launch_bounds__(256)
void attn_kernel(const bf16* __restrict__ qkv, const int* __restrict__ cbuf,
                 const float* __restrict__ biasL, bf16* __restrict__ O)
{
  __shared__ __align__(16) bf16 Plds[4][256];    // 16x16 per wave
  __shared__ __align__(16) bf16 Vt[4][1024];     // 64x16 per wave (v^T, cols j>=10 zero)
  const int w = threadIdx.x >> 6, lane = threadIdx.x & 63;
  const int wv = blockIdx.x * 4 + w;
  const int b = wv >> 3, h = wv & 7;
  const int r = lane & 15, g = lane >> 4;
  const bf16* base = qkv + (size_t)b * 15360;    // 10*1536
  const bool rv = r < 10;
  const short8v z8 = {0,0,0,0,0,0,0,0};

  short8v aq0 = z8, aq1 = z8, bk0 = z8, bk1 = z8;
  if (rv) {
    const bf16* qp = base + (size_t)r * 1536 + h * 64 + g * 8;
    aq0 = *(const short8v*)qp;
    aq1 = *(const short8v*)(qp + 32);
    bk0 = *(const short8v*)(qp + 512);
    bk1 = *(const short8v*)(qp + 544);
  }
  f32x4 s = {0.f, 0.f, 0.f, 0.f};
  s = __builtin_amdgcn_mfma_f32_16x16x32_bf16(aq0, bk0, s, 0, 0, 0);
  s = __builtin_amdgcn_mfma_f32_16x16x32_bf16(aq1, bk1, s, 0, 0, 0);

  bf16* V = Vt[w];
  {
    const int j1 = lane >> 3, d0 = (lane & 7) * 8;
    U8 uv; uv.v = *(const short8v*)(base + (size_t)j1 * 1536 + 1024 + h * 64 + d0);
    #pragma unroll
    for (int m2 = 0; m2 < 8; ++m2) V[(d0 + m2) * 16 + j1] = uv.h[m2];
    const int j2 = 8 + j1;
    U8 uv2; uv2.v = z8;
    if (j2 < 10) uv2.v = *(const short8v*)(base + (size_t)j2 * 1536 + 1024 + h * 64 + d0);
    #pragma unroll
    for (int m2 = 0; m2 < 8; ++m2) V[(d0 + m2) * 16 + j2] = uv2.h[m2];
  }

  const int cj = rv ? cbuf[b * 10 + r] : 0;
  float sv[4];
  #pragma unroll
  for (int q4 = 0; q4 < 4; ++q4) {
    const int i = g * 4 + q4;
    float val = s[q4] * 0.125f;                       // 1/sqrt(64)
    if (rv && i < 10) val += biasL[h * 100 + cbuf[b * 10 + i] * 10 + cj];
    if (!rv) val = -1e30f;
    sv[q4] = val;
  }
  float mx[4];
  #pragma unroll
  for (int q4 = 0; q4 < 4; ++q4) mx[q4] = sv[q4];
  for (int d0 = 1; d0 < 16; d0 <<= 1) {
    #pragma unroll
    for (int q4 = 0; q4 < 4; ++q4) mx[q4] = fmaxf(mx[q4], __shfl_xor(mx[q4], d0));
  }
  float pe[4], sm[4];
  #pragma unroll
  for (int q4 = 0; q4 < 4; ++q4) { pe[q4] = __expf(sv[q4] - mx[q4]); sm[q4] = pe[q4]; }
  for (int d0 = 1; d0 < 16; d0 <<= 1) {
    #pragma unroll
    for (int q4 = 0; q4 < 4; ++q4) sm[q4] += __shfl_xor(sm[q4], d0);
  }

  bf16* P = Plds[w];
  #pragma unroll
  for (int q4 = 0; q4 < 4; ++q4) P[(g * 4 + q4) * 16 + r] = f2bf(pe[q4] / sm[q4]);

  short8v pa = z8;
  if (g < 2) pa = *(const short8v*)&P[r * 16 + g * 8];
  #pragma unroll
  for (int db = 0; db < 4; ++db) {
    short8v bv = z8;
    if (g < 2) bv = *(const short8v*)&V[(db * 16 + r) * 16 + g * 8];
    f32x4 o = {0.f, 0.f, 0.f, 0.f};
    o = __builtin_amdgcn_mfma_f32_16x16x32_bf16(pa, bv, o, 0, 0, 0);
    #pragma unroll
    for (int q4 = 0; q4 < 4; ++q4) {
      const int i = g * 4 + q4;
      if (i < 10) O[(size_t)(b * 10 + i) * 512 + h * 64 + db * 16 + r] = f2bf(o[q4]);
    }
  }
}

// ---------------------------------------------------------------- token mean: (8192,10,512) f32 -> (8192,512) bf16
__global__ __launch_bounds__(256)
void mean_kernel(const float* __restrict__ Zin, bf16* __restrict__ zm)
{
  const int idx = blockIdx.x * 256 + threadIdx.x;   // 8192*128
  const int b = idx >> 7, d4 = (idx & 127) << 2;
  const float* p = Zin + (size_t)b * 5120 + d4;
  f32x4 a = {0.f, 0.f, 0.f, 0.f};
  #pragma unroll
  for (int i = 0; i < 10; ++i) a += *(const f32x4*)(p + (size_t)i * 512);
  a *= 0.1f;
  U4 u;
  #pragma unroll
  for (int j = 0; j < 4; ++j) u.h[j] = f2bf(a[j]);
  *(short4v*)(zm + (size_t)b * 512 + d4) = u.v;
}

// ---------------------------------------------------------------- head2: (8192,512)bf16 @ (512,5)f32 + b2
__global__ __launch_bounds__(256)
void head2_kernel(const bf16* __restrict__ hh, const float* __restrict__ W2,
                  const float* __restrict__ b2, float* __restrict__ out)
{
  const int w = threadIdx.x >> 6, lane = threadIdx.x & 63;
  const int b = blockIdx.x * 4 + w;
  U8 u; u.v = *(const short8v*)(hh + (size_t)b * 512 + lane * 8);
  float p[5] = {0.f, 0.f, 0.f, 0.f, 0.f};
  #pragma unroll
  for (int j = 0; j < 8; ++j) {
    const float hf = bf2f(u.h[j]);
    const float* wp = W2 + (size_t)(lane * 8 + j) * 5;
    #pragma unroll
    for (int c = 0; c < 5; ++c) p[c] += hf * wp[c];
  }
  for (int d0 = 1; d0 < 64; d0 <<= 1) {
    #pragma unroll
    for (int c = 0; c < 5; ++c) p[c] += __shfl_xor(p[c], d0);
  }
  if (lane == 0) {
    float* op = out + (size_t)b * 5;
    #pragma unroll
    for (int c = 0; c < 5; ++c) op[c] = p[c] + b2[c];
  }
}

// ----------------------------------------------------------------
extern "C" void kernel_launch(void* const* d_in, const int* in_sizes, int n_in,
                              void* d_out, int out_size, void* d_ws, size_t ws_size,
                              hipStream_t stream)
{
  const int*   off_ids = (const int*)d_in[0];
  const int*   def_ids = (const int*)d_in[1];
  const int*   off_pos = (const int*)d_in[2];
  const int*   def_pos = (const int*)d_in[3];
  const float* pemb    = (const float*)d_in[4];
  const float* remb    = (const float*)d_in[5];
  const float* proj_W1 = (const float*)d_in[6];
  const float* proj_b1 = (const float*)d_in[7];
  const float* proj_W2 = (const float*)d_in[8];
  const float* proj_b2 = (const float*)d_in[9];
  const float* ln1_g   = (const float*)d_in[10];
  const float* ln1_b   = (const float*)d_in[11];
  const float* Wq      = (const float*)d_in[12];
  const float* Wk      = (const float*)d_in[13];
  const float* Wv      = (const float*)d_in[14];
  const float* Wo      = (const float*)d_in[15];
  const float* bias_B  = (const float*)d_in[16];
  const float* ln2_g   = (const float*)d_in[17];
  const float* ln2_b   = (const float*)d_in[18];
  const float* ffn_W1  = (const float*)d_in[19];
  const float* ffn_b1  = (const float*)d_in[20];
  const float* ffn_W2  = (const float*)d_in[21];
  const float* ffn_b2  = (const float*)d_in[22];
  const float* head_W1 = (const float*)d_in[23];
  const float* head_b1 = (const float*)d_in[24];
  const float* head_W2 = (const float*)d_in[25];
  const float* head_b2 = (const float*)d_in[26];
  (void)in_sizes; (void)n_in; (void)out_size;

  char* ws = (char*)d_ws;
  size_t off = 0;
  auto take = [&](size_t bytes) -> char* {
    char* p = ws + off; off += (bytes + 255) & ~(size_t)255; return p;
  };

  // ---- fixed allocations first
  float* Z     = (float*)take(81920ull * 512 * 4);       // residual, f32 (160MiB)
  bf16*  Wp1T  = (bf16*)take(1024ull * 1024 * 2);
  bf16*  Wp2T  = (bf16*)take(512ull * 1024 * 2);
  bf16*  Wh1T  = (bf16*)take(512ull * 512 * 2);
  bf16*  WqkvT = (bf16*)take(4ull * 1536 * 512 * 2);
  bf16*  WoT   = (bf16*)take(4ull * 512 * 512 * 2);
  bf16*  Wf1T  = (bf16*)take(4ull * 2048 * 512 * 2);
  bf16*  Wf2T  = (bf16*)take(4ull * 512 * 2048 * 2);
  int*   cbuf  = (int*)take(81920ull * 4);
  bf16*  zmean = (bf16*)take(8192ull * 512 * 2);
  bf16*  hh    = (bf16*)take(8192ull * 512 * 2);

  // ---- adaptive M-chunk: arena = Mc * 5KB must fit in remaining ws
  const size_t fixed_end = off;
  int Mc = 81920;
  while (Mc > 2560 && fixed_end + (size_t)Mc * 5120 + (1u << 20) > ws_size) Mc >>= 1;
  const int NCH = 81920 / Mc;
  char* arena = ws + fixed_end;

  // ---- weight transpose+convert (f32 (K,N) -> bf16 (N,K)), batched over layers
  auto T = [&](const float* W, bf16* WT, int K, int N, size_t sW, size_t sWT, int nz) {
    transpose_w<<<dim3(N / 32, K / 32, nz), 256, 0, stream>>>(W, WT, K, N, sW, sWT);
  };
  T(proj_W1, Wp1T, 1024, 1024, 0, 0, 1);
  T(proj_W2, Wp2T, 1024, 512, 0, 0, 1);
  T(head_W1, Wh1T, 512, 512, 0, 0, 1);
  T(Wq, WqkvT,          512, 512, 262144, 786432, 4);
  T(Wk, WqkvT + 262144, 512, 512, 262144, 786432, 4);
  T(Wv, WqkvT + 524288, 512, 512, 262144, 786432, 4);
  T(Wo, WoT,            512, 512, 262144, 262144, 4);
  T(ffn_W1, Wf1T, 512, 2048, 1048576, 1048576, 4);
  T(ffn_W2, Wf2T, 2048, 512, 1048576, 1048576, 4);

  // ---- embed gather + proj MLP (chunked)
  for (int c = 0; c < NCH; ++c) {
    const int r0 = c * Mc;
    bf16* Xc  = (bf16*)arena;                          // Mc x 1024 bf16
    bf16* H1c = (bf16*)(arena + (size_t)Mc * 2048);    // Mc x 1024 bf16
    gather_kernel<<<Mc, 256, 0, stream>>>(off_ids, def_ids, off_pos, def_pos,
                                          pemb, remb, r0, Xc, cbuf);
    gemm256<true,  true,  false, true ><<<dim3(4, Mc/256), 512, 0, stream>>>(Xc,  Wp1T, proj_b1, nullptr, H1c, Mc, 1024, 1024);
    gemm256<false, true,  false, false><<<dim3(2, Mc/256), 512, 0, stream>>>(H1c, Wp2T, proj_b2, nullptr, Z + (size_t)r0 * 512, Mc, 512, 1024);
  }

  // ---- transformer layers (chunked)
  for (int l = 0; l < 4; ++l) {
    for (int c = 0; c < NCH; ++c) {                    // attention sub-block
      const int r0 = c * Mc;
      float* Zc = Z + (size_t)r0 * 512;
      bf16* Z1c  = (bf16*)arena;                       // Mc x 512
      bf16* QKVc = (bf16*)(arena + (size_t)Mc * 1024); // Mc x 1536
      bf16* Oc   = (bf16*)(arena + (size_t)Mc * 4096); // Mc x 512
      ln_kernel<<<Mc/4, 256, 0, stream>>>(Zc, ln1_g + l*512, ln1_b + l*512, Z1c);
      gemm256<false, false, false, true ><<<dim3(6, Mc/256), 512, 0, stream>>>(Z1c, WqkvT + (size_t)l * 786432, nullptr, nullptr, QKVc, Mc, 1536, 512);
      attn_kernel<<<Mc/5, 256, 0, stream>>>(QKVc, cbuf + r0, bias_B + (size_t)l * 800, Oc);
      gemm256<false, false, true,  false><<<dim3(2, Mc/256), 512, 0, stream>>>(Oc, WoT + (size_t)l * 262144, nullptr, Zc, Zc, Mc, 512, 512);
    }
    for (int c = 0; c < NCH; ++c) {                    // FFN sub-block
      const int r0 = c * Mc;
      float* Zc = Z + (size_t)r0 * 512;
      bf16* Z2c = (bf16*)arena;                        // Mc x 512
      bf16* Hc  = (bf16*)(arena + (size_t)Mc * 1024);  // Mc x 2048
      ln_kernel<<<Mc/4, 256, 0, stream>>>(Zc, ln2_g + l*512, ln2_b + l*512, Z2c);
      gemm256<true,  true,  false, true ><<<dim3(8, Mc/256), 512, 0, stream>>>(Z2c, Wf1T + (size_t)l * 1048576, ffn_b1 + (size_t)l * 2048, nullptr, Hc, Mc, 2048, 512);
      gemm256<false, true,  true,  false><<<dim3(2, Mc/256), 512, 0, stream>>>(Hc, Wf2T + (size_t)l * 1048576, ffn_b2 + (size_t)l * 512, Zc, Zc, Mc, 512, 2048);
    }
  }

  // ---- head
  mean_kernel<<<4096, 256, 0, stream>>>(Z, zmean);
  gemm256<true, true, false, true><<<dim3(2, 32), 512, 0, stream>>>(zmean, Wh1T, head_b1, nullptr, hh, 8192, 512, 512);
  head2_kernel<<<2048, 256, 0, stream>>>(hh, head_W2, head_b2, (float*)d_out);
}

// Round 8
// 5115.483 us; speedup vs baseline: 1.5499x; 1.5499x over previous
//
#include <hip/hip_runtime.h>
#include <hip/hip_bf16.h>
#include <stdint.h>

typedef __hip_bfloat16 bf16;
typedef __attribute__((ext_vector_type(4))) float f32x4;
typedef __attribute__((ext_vector_type(8))) short short8v;
typedef __attribute__((ext_vector_type(4))) short short4v;

union U8 { short8v v; bf16 h[8]; };
union U4 { short4v v; bf16 h[4]; };

#define DEV static __device__ __forceinline__

DEV bf16 f2bf(float f) { return __float2bfloat16(f); }
DEV float bf2f(bf16 h) { return __bfloat162float(h); }

DEV void async_copy16(bf16* lds, const bf16* g) {
  __builtin_amdgcn_global_load_lds(
      (const __attribute__((address_space(1))) unsigned int*)g,
      (__attribute__((address_space(3))) unsigned int*)lds,
      16, 0, 0);
}

// ---------------------------------------------------------------- GEMM 128x128
// C(M,N) = act( A(M,K)bf16 @ BT(N,K)^T + bias + Cin ), 4 waves, BK=32.
// Double-buffer 2-phase (structure proven passing in r6): STAGE(t+1) issued
// BEFORE compute(t); single __syncthreads per iter drains vmcnt(0).
template<bool RELU, bool BIAS, bool ADDC, bool OBF16>
__global__ __launch_bounds__(256)
void gemm128(const bf16* __restrict__ A, const bf16* __restrict__ BT,
             const float* __restrict__ bias, const float* __restrict__ Cin,
             void* __restrict__ Dout, int M, int N, int K)
{
  __shared__ __align__(16) bf16 lds[16384];   // 2 bufs x (A 4096 + B 4096 elems)
  const int tid = threadIdx.x;
  const int m0 = blockIdx.y * 128, n0 = blockIdx.x * 128;
  const int wid = tid >> 6, lane = tid & 63;
  const int wr = wid >> 1, wc = wid & 1;
  const int r = lane & 15, g = lane >> 4;

  const int srow = tid >> 2;                   // 0..63
  const int scol = (tid & 3) * 8;
  const bf16* a0 = A  + (size_t)(m0 + srow) * K + scol;
  const bf16* a1 = A  + (size_t)(m0 + srow + 64) * K + scol;
  const bf16* b0 = BT + (size_t)(n0 + srow) * K + scol;
  const bf16* b1 = BT + (size_t)(n0 + srow + 64) * K + scol;

  const int NT = K >> 5;

  f32x4 acc[4][4];
  #pragma unroll
  for (int i = 0; i < 4; ++i)
    #pragma unroll
    for (int j = 0; j < 4; ++j) acc[i][j] = (f32x4){0.f, 0.f, 0.f, 0.f};

  auto STAGE = [&](int t, int buf) {           // 4 x 16B per thread
    bf16* dst = &lds[buf * 8192];
    const int kt = t << 5;
    async_copy16(dst +         tid * 8, a0 + kt);
    async_copy16(dst + 2048 +  tid * 8, a1 + kt);
    async_copy16(dst + 4096 +  tid * 8, b0 + kt);
    async_copy16(dst + 6144 +  tid * 8, b1 + kt);
  };

  STAGE(0, 0);
  __syncthreads();
  int cur = 0;
  for (int t = 0; t < NT; ++t) {
    if (t + 1 < NT) STAGE(t + 1, cur ^ 1);     // in flight during compute below

    const bf16* Ab = &lds[cur * 8192];
    const bf16* Bb = Ab + 4096;
    short8v af[4], bfr[4];
    #pragma unroll
    for (int mi = 0; mi < 4; ++mi)
      af[mi] = *(const short8v*)&Ab[(wr*64 + mi*16 + r) * 32 + g*8];
    #pragma unroll
    for (int ni = 0; ni < 4; ++ni)
      bfr[ni] = *(const short8v*)&Bb[(wc*64 + ni*16 + r) * 32 + g*8];

    __builtin_amdgcn_s_setprio(1);
    #pragma unroll
    for (int mi = 0; mi < 4; ++mi)
      #pragma unroll
      for (int ni = 0; ni < 4; ++ni)
        acc[mi][ni] = __builtin_amdgcn_mfma_f32_16x16x32_bf16(af[mi], bfr[ni], acc[mi][ni], 0, 0, 0);
    __builtin_amdgcn_s_setprio(0);

    __syncthreads();                           // next tile landed; reads done
    cur ^= 1;
  }

  const int mbase = m0 + wr*64;
  const int nbase = n0 + wc*64;
  #pragma unroll
  for (int ni = 0; ni < 4; ++ni) {
    const int col = nbase + ni*16 + r;
    const float bv = BIAS ? bias[col] : 0.f;
    #pragma unroll
    for (int mi = 0; mi < 4; ++mi) {
      #pragma unroll
      for (int b4 = 0; b4 < 4; ++b4) {
        const int row = mbase + mi*16 + g*4 + b4;
        float v = acc[mi][ni][b4] + bv;
        if (ADDC) v += Cin[(size_t)row * N + col];
        if (RELU) v = fmaxf(v, 0.f);
        if (OBF16) ((bf16*)Dout)[(size_t)row * N + col] = f2bf(v);
        else       ((float*)Dout)[(size_t)row * N + col] = v;
      }
    }
  }
}

// ---------------------------------------------------------------- weights: W(K,N) f32 -> WT(N,K) bf16 (batched over z)
__global__ __launch_bounds__(256)
void transpose_w(const float* __restrict__ W, bf16* __restrict__ WT, int K, int N,
                 size_t sW, size_t sWT)
{
  const float* Wp = W + (size_t)blockIdx.z * sW;
  bf16* WTp = WT + (size_t)blockIdx.z * sWT;
  __shared__ float tl[32][33];
  const int n0 = blockIdx.x * 32, k0 = blockIdx.y * 32;
  const int r = threadIdx.x >> 5, c = threadIdx.x & 31;
  #pragma unroll
  for (int rr = r; rr < 32; rr += 8) tl[rr][c] = Wp[(size_t)(k0 + rr) * N + n0 + c];
  __syncthreads();
  #pragma unroll
  for (int rr = r; rr < 32; rr += 8) WTp[(size_t)(n0 + rr) * K + k0 + c] = f2bf(tl[c][rr]);
}

// ---------------------------------------------------------------- pad pemb chunk: rows [p0, p0+1280) -> Apad_c (1280x512 bf16)
__global__ __launch_bounds__(128)
void pad_pemb(const float* __restrict__ pemb, bf16* __restrict__ Apad, int p0)
{
  const int lrow = blockIdx.x;           // 0..1279
  const int grow = p0 + lrow;
  const int c = threadIdx.x * 4;
  U4 u;
  if (grow < 5000) {
    f32x4 v = *(const f32x4*)(pemb + (size_t)grow * 512 + c);
    u.h[0]=f2bf(v[0]); u.h[1]=f2bf(v[1]); u.h[2]=f2bf(v[2]); u.h[3]=f2bf(v[3]);
  } else {
    u.v = (short4v){0,0,0,0};
  }
  *(short4v*)(Apad + (size_t)lrow * 512 + c) = u.v;
}

// ---------------------------------------------------------------- pad remb (2x512 f32) -> Rpad (128x512 bf16, pad=0)
__global__ __launch_bounds__(128)
void pad_remb(const float* __restrict__ remb, bf16* __restrict__ Rpad)
{
  const int row = blockIdx.x;            // 0..127
  const int c = threadIdx.x * 4;
  U4 u;
  if (row < 2) {
    f32x4 v = *(const f32x4*)(remb + (size_t)row * 512 + c);
    u.h[0]=f2bf(v[0]); u.h[1]=f2bf(v[1]); u.h[2]=f2bf(v[2]); u.h[3]=f2bf(v[3]);
  } else {
    u.v = (short4v){0,0,0,0};
  }
  *(short4v*)(Rpad + (size_t)row * 512 + c) = u.v;
}

// ---------------------------------------------------------------- H1 chunk: relu(PW1_c[p] + RW1[role]) -> bf16 (2560x1024)
__global__ __launch_bounds__(256)
void h1tab_kernel(const bf16* __restrict__ PW1c, const float* __restrict__ RW1,
                  bf16* __restrict__ H1c)
{
  const int row = blockIdx.x;            // 0..2559 : p_local*2+role
  const int p = row >> 1, role = row & 1;
  const int c = threadIdx.x * 4;
  U4 a; a.v = *(const short4v*)(PW1c + (size_t)p * 1024 + c);
  f32x4 rv = *(const f32x4*)(RW1 + (size_t)role * 1024 + c);
  U4 o;
  #pragma unroll
  for (int j = 0; j < 4; ++j) o.h[j] = f2bf(fmaxf(bf2f(a.h[j]) + rv[j], 0.f));
  *(short4v*)(H1c + (size_t)row * 1024 + c) = o.v;
}

// ---------------------------------------------------------------- Z0 gather: Z[row] = f32(Z0tab[pid*2+role]); also cbuf
__global__ __launch_bounds__(128)
void z0_gather(const int* __restrict__ off_ids, const int* __restrict__ def_ids,
               const int* __restrict__ off_pos, const int* __restrict__ def_pos,
               const bf16* __restrict__ Z0tab, float* __restrict__ Z,
               int* __restrict__ cbuf)
{
  const int row = blockIdx.x;            // 0..81919
  const int b = row / 10, t = row % 10;
  int pid, pos, role;
  if (t < 5) { pid = off_ids[b*5 + t];   pos = off_pos[b*5 + t];   role = 0; }
  else       { pid = def_ids[b*5 + t-5]; pos = def_pos[b*5 + t-5]; role = 1; }
  if (threadIdx.x == 0) cbuf[row] = role * 5 + pos;
  const int c = threadIdx.x * 4;
  U4 u; u.v = *(const short4v*)(Z0tab + (size_t)(pid * 2 + role) * 512 + c);
  f32x4 v;
  #pragma unroll
  for (int j = 0; j < 4; ++j) v[j] = bf2f(u.h[j]);
  *(f32x4*)(Z + (size_t)row * 512 + c) = v;
}

// ---------------------------------------------------------------- LayerNorm rows of 512, f32 in -> bf16 out
__global__ __launch_bounds__(256)
void ln_kernel(const float* __restrict__ Zin, const float* __restrict__ gam,
               const float* __restrict__ bet, bf16* __restrict__ outp)
{
  const int w = threadIdx.x >> 6, lane = threadIdx.x & 63;
  const size_t row = (size_t)blockIdx.x * 4 + w;
  const float* zp = Zin + row * 512 + lane * 8;
  f32x4 v0 = *(const f32x4*)zp;
  f32x4 v1 = *(const f32x4*)(zp + 4);
  float s = 0.f, ss = 0.f;
  #pragma unroll
  for (int j = 0; j < 4; ++j) { s += v0[j]; ss += v0[j]*v0[j]; }
  #pragma unroll
  for (int j = 0; j < 4; ++j) { s += v1[j]; ss += v1[j]*v1[j]; }
  for (int d0 = 1; d0 < 64; d0 <<= 1) { s += __shfl_xor(s, d0); ss += __shfl_xor(ss, d0); }
  const float mu = s * (1.f/512.f);
  const float rstd = rsqrtf(ss * (1.f/512.f) - mu*mu + 1e-5f);
  const float* gp = gam + lane * 8;
  const float* bp = bet + lane * 8;
  f32x4 g0 = *(const f32x4*)gp, g1 = *(const f32x4*)(gp + 4);
  f32x4 b0 = *(const f32x4*)bp, b1 = *(const f32x4*)(bp + 4);
  U8 u;
  #pragma unroll
  for (int j = 0; j < 4; ++j) u.h[j]     = f2bf((v0[j]-mu)*rstd*g0[j] + b0[j]);
  #pragma unroll
  for (int j = 0; j < 4; ++j) u.h[4 + j] = f2bf((v1[j]-mu)*rstd*g1[j] + b1[j]);
  *(short8v*)(outp + row * 512 + lane * 8) = u.v;
}

// ---------------------------------------------------------------- attention: one wave per (local b, h)
__global__ __launch_bounds__(256)
void attn_kernel(const bf16* __restrict__ qkv, const int* __restrict__ cbuf,
                 const float* __restrict__ biasL, bf16* __restrict__ O)
{
  __shared__ __align__(16) bf16 Plds[4][256];
  __shared__ __align__(16) bf16 Vt[4][1024];
  const int w = threadIdx.x >> 6, lane = threadIdx.x & 63;
  const int wv = blockIdx.x * 4 + w;
  const int b = wv >> 3, h = wv & 7;
  const int r = lane & 15, g = lane >> 4;
  const bf16* base = qkv + (size_t)b * 15360;
  const bool rv = r < 10;
  const short8v z8 = {0,0,0,0,0,0,0,0};

  short8v aq0 = z8, aq1 = z8, bk0 = z8, bk1 = z8;
  if (rv) {
    const bf16* qp = base + (size_t)r * 1536 + h * 64 + g * 8;
    aq0 = *(const short8v*)qp;
    aq1 = *(const short8v*)(qp + 32);
    bk0 = *(const short8v*)(qp + 512);
    bk1 = *(const short8v*)(qp + 544);
  }
  f32x4 s = {0.f, 0.f, 0.f, 0.f};
  s = __builtin_amdgcn_mfma_f32_16x16x32_bf16(aq0, bk0, s, 0, 0, 0);
  s = __builtin_amdgcn_mfma_f32_16x16x32_bf16(aq1, bk1, s, 0, 0, 0);

  bf16* V = Vt[w];
  {
    const int j1 = lane >> 3, d0 = (lane & 7) * 8;
    U8 uv; uv.v = *(const short8v*)(base + (size_t)j1 * 1536 + 1024 + h * 64 + d0);
    #pragma unroll
    for (int m2 = 0; m2 < 8; ++m2) V[(d0 + m2) * 16 + j1] = uv.h[m2];
    const int j2 = 8 + j1;
    U8 uv2; uv2.v = z8;
    if (j2 < 10) uv2.v = *(const short8v*)(base + (size_t)j2 * 1536 + 1024 + h * 64 + d0);
    #pragma unroll
    for (int m2 = 0; m2 < 8; ++m2) V[(d0 + m2) * 16 + j2] = uv2.h[m2];
  }

  const int cj = rv ? cbuf[b * 10 + r] : 0;
  float sv[4];
  #pragma unroll
  for (int q4 = 0; q4 < 4; ++q4) {
    const int i = g * 4 + q4;
    float val = s[q4] * 0.125f;
    if (rv && i < 10) val += biasL[h * 100 + cbuf[b * 10 + i] * 10 + cj];
    if (!rv) val = -1e30f;
    sv[q4] = val;
  }
  float mx[4];
  #pragma unroll
  for (int q4 = 0; q4 < 4; ++q4) mx[q4] = sv[q4];
  for (int d0 = 1; d0 < 16; d0 <<= 1) {
    #pragma unroll
    for (int q4 = 0; q4 < 4; ++q4) mx[q4] = fmaxf(mx[q4], __shfl_xor(mx[q4], d0));
  }
  float pe[4], sm[4];
  #pragma unroll
  for (int q4 = 0; q4 < 4; ++q4) { pe[q4] = __expf(sv[q4] - mx[q4]); sm[q4] = pe[q4]; }
  for (int d0 = 1; d0 < 16; d0 <<= 1) {
    #pragma unroll
    for (int q4 = 0; q4 < 4; ++q4) sm[q4] += __shfl_xor(sm[q4], d0);
  }

  bf16* P = Plds[w];
  #pragma unroll
  for (int q4 = 0; q4 < 4; ++q4) P[(g * 4 + q4) * 16 + r] = f2bf(pe[q4] / sm[q4]);

  short8v pa = z8;
  if (g < 2) pa = *(const short8v*)&P[r * 16 + g * 8];
  #pragma unroll
  for (int db = 0; db < 4; ++db) {
    short8v bv = z8;
    if (g < 2) bv = *(const short8v*)&V[(db * 16 + r) * 16 + g * 8];
    f32x4 o = {0.f, 0.f, 0.f, 0.f};
    o = __builtin_amdgcn_mfma_f32_16x16x32_bf16(pa, bv, o, 0, 0, 0);
    #pragma unroll
    for (int q4 = 0; q4 < 4; ++q4) {
      const int i = g * 4 + q4;
      if (i < 10) O[(size_t)(b * 10 + i) * 512 + h * 64 + db * 16 + r] = f2bf(o[q4]);
    }
  }
}

// ---------------------------------------------------------------- token mean
__global__ __launch_bounds__(256)
void mean_kernel(const float* __restrict__ Zin, bf16* __restrict__ zm)
{
  const int idx = blockIdx.x * 256 + threadIdx.x;
  const int b = idx >> 7, d4 = (idx & 127) << 2;
  const float* p = Zin + (size_t)b * 5120 + d4;
  f32x4 a = {0.f, 0.f, 0.f, 0.f};
  #pragma unroll
  for (int i = 0; i < 10; ++i) a += *(const f32x4*)(p + (size_t)i * 512);
  a *= 0.1f;
  U4 u;
  #pragma unroll
  for (int j = 0; j < 4; ++j) u.h[j] = f2bf(a[j]);
  *(short4v*)(zm + (size_t)b * 512 + d4) = u.v;
}

// ---------------------------------------------------------------- head2
__global__ __launch_bounds__(256)
void head2_kernel(const bf16* __restrict__ hh, const float* __restrict__ W2,
                  const float* __restrict__ b2, float* __restrict__ out)
{
  const int w = threadIdx.x >> 6, lane = threadIdx.x & 63;
  const int b = blockIdx.x * 4 + w;
  U8 u; u.v = *(const short8v*)(hh + (size_t)b * 512 + lane * 8);
  float p[5] = {0.f, 0.f, 0.f, 0.f, 0.f};
  #pragma unroll
  for (int j = 0; j < 8; ++j) {
    const float hf = bf2f(u.h[j]);
    const float* wp = W2 + (size_t)(lane * 8 + j) * 5;
    #pragma unroll
    for (int c = 0; c < 5; ++c) p[c] += hf * wp[c];
  }
  for (int d0 = 1; d0 < 64; d0 <<= 1) {
    #pragma unroll
    for (int c = 0; c < 5; ++c) p[c] += __shfl_xor(p[c], d0);
  }
  if (lane == 0) {
    float* op = out + (size_t)b * 5;
    #pragma unroll
    for (int c = 0; c < 5; ++c) op[c] = p[c] + b2[c];
  }
}

// ----------------------------------------------------------------
extern "C" void kernel_launch(void* const* d_in, const int* in_sizes, int n_in,
                              void* d_out, int out_size, void* d_ws, size_t ws_size,
                              hipStream_t stream)
{
  const int*   off_ids = (const int*)d_in[0];
  const int*   def_ids = (const int*)d_in[1];
  const int*   off_pos = (const int*)d_in[2];
  const int*   def_pos = (const int*)d_in[3];
  const float* pemb    = (const float*)d_in[4];
  const float* remb    = (const float*)d_in[5];
  const float* proj_W1 = (const float*)d_in[6];
  const float* proj_b1 = (const float*)d_in[7];
  const float* proj_W2 = (const float*)d_in[8];
  const float* proj_b2 = (const float*)d_in[9];
  const float* ln1_g   = (const float*)d_in[10];
  const float* ln1_b   = (const float*)d_in[11];
  const float* Wq      = (const float*)d_in[12];
  const float* Wk      = (const float*)d_in[13];
  const float* Wv      = (const float*)d_in[14];
  const float* Wo      = (const float*)d_in[15];
  const float* bias_B  = (const float*)d_in[16];
  const float* ln2_g   = (const float*)d_in[17];
  const float* ln2_b   = (const float*)d_in[18];
  const float* ffn_W1  = (const float*)d_in[19];
  const float* ffn_b1  = (const float*)d_in[20];
  const float* ffn_W2  = (const float*)d_in[21];
  const float* ffn_b2  = (const float*)d_in[22];
  const float* head_W1 = (const float*)d_in[23];
  const float* head_b1 = (const float*)d_in[24];
  const float* head_W2 = (const float*)d_in[25];
  const float* head_b2 = (const float*)d_in[26];
  (void)in_sizes; (void)n_in; (void)out_size;

  char* ws = (char*)d_ws;
  size_t off = 0;
  auto take = [&](size_t bytes) -> char* {
    char* p = ws + off; off += (bytes + 255) & ~(size_t)255; return p;
  };

  // ---- fixed allocations (~204 MiB, matches proven-passing rounds)
  float* Z      = (float*)take(81920ull * 512 * 4);     // residual f32 (160MiB)
  bf16*  W1topT = (bf16*)take(1024ull * 512 * 2);
  bf16*  W1botT = (bf16*)take(1024ull * 512 * 2);
  bf16*  Wp2T   = (bf16*)take(512ull * 1024 * 2);
  bf16*  Wh1T   = (bf16*)take(512ull * 512 * 2);
  bf16*  WqkvT  = (bf16*)take(4ull * 1536 * 512 * 2);
  bf16*  WoT    = (bf16*)take(4ull * 512 * 512 * 2);
  bf16*  Wf1T   = (bf16*)take(4ull * 2048 * 512 * 2);
  bf16*  Wf2T   = (bf16*)take(4ull * 512 * 2048 * 2);
  int*   cbuf   = (int*)take(81920ull * 4);
  bf16*  zmean  = (bf16*)take(8192ull * 512 * 2);       // }
  bf16*  hh     = (bf16*)take(8192ull * 512 * 2);       // } 16MiB, reused as prologue chunk bufs

  // ---- adaptive M-chunk (identical formula to passing rounds; min-need unchanged)
  const size_t fixed_end = off;
  int Mc = 81920;
  while (Mc > 2560 && fixed_end + (size_t)Mc * 5120 + (1u << 20) > ws_size) Mc >>= 1;
  const int NCH = 81920 / Mc;
  char* arena = ws + fixed_end;

  // ---- prologue scratch overlays:
  //   Z0tab (10MiB bf16) in arena (<= 12.5MiB floor; dead before layer loop)
  //   chunk buffers (~9.8MB) overlay zmean+hh (16MiB contiguous; dead until head)
  bf16* Z0tab = (bf16*)arena;                           // 10240 x 512 bf16
  char* tb = (char*)zmean;
  auto ttake = [&](size_t bytes) -> char* {
    char* p = tb; tb += (bytes + 255) & ~(size_t)255; return p;
  };
  bf16*  Rpad  = (bf16*)ttake(128ull * 512 * 2);
  float* RW1   = (float*)ttake(128ull * 1024 * 4);
  bf16*  ApadC = (bf16*)ttake(1280ull * 512 * 2);
  bf16*  PW1C  = (bf16*)ttake(1280ull * 1024 * 2);
  bf16*  H1C   = (bf16*)ttake(2560ull * 1024 * 2);

  // ---- weight transpose+convert (f32 (K,N) -> bf16 (N,K))
  auto T = [&](const float* W, bf16* WT, int K, int N, size_t sW, size_t sWT, int nz) {
    transpose_w<<<dim3(N / 32, K / 32, nz), 256, 0, stream>>>(W, WT, K, N, sW, sWT);
  };
  T(proj_W1,               W1topT, 512, 1024, 0, 0, 1);   // W1 rows 0..511   (e half)
  T(proj_W1 + 512ull*1024, W1botT, 512, 1024, 0, 0, 1);   // W1 rows 512..1023 (r half)
  T(proj_W2, Wp2T, 1024, 512, 0, 0, 1);
  T(head_W1, Wh1T, 512, 512, 0, 0, 1);
  T(Wq, WqkvT,          512, 512, 262144, 786432, 4);
  T(Wk, WqkvT + 262144, 512, 512, 262144, 786432, 4);
  T(Wv, WqkvT + 524288, 512, 512, 262144, 786432, 4);
  T(Wo, WoT,            512, 512, 262144, 262144, 4);
  T(ffn_W1, Wf1T, 512, 2048, 1048576, 1048576, 4);
  T(ffn_W2, Wf2T, 2048, 512, 1048576, 1048576, 4);

  // ---- prologue: Z0tab[(pid,role)] replaces proj MLP on all 81920 rows
  pad_remb<<<128, 128, 0, stream>>>(remb, Rpad);
  gemm128<false, true, false, false><<<dim3(8, 1), 256, 0, stream>>>(Rpad, W1botT, proj_b1, nullptr, RW1, 128, 1024, 512);
  for (int pc = 0; pc < 4; ++pc) {                      // 1280 players / chunk
    pad_pemb<<<1280, 128, 0, stream>>>(pemb, ApadC, pc * 1280);
    gemm128<false, false, false, true ><<<dim3(8, 10), 256, 0, stream>>>(ApadC, W1topT, nullptr, nullptr, PW1C, 1280, 1024, 512);
    h1tab_kernel<<<2560, 256, 0, stream>>>(PW1C, RW1, H1C);
    gemm128<false, true,  false, true ><<<dim3(4, 20), 256, 0, stream>>>(H1C, Wp2T, proj_b2, nullptr, Z0tab + (size_t)pc * 2560 * 512, 2560, 512, 1024);
  }
  z0_gather<<<81920, 128, 0, stream>>>(off_ids, def_ids, off_pos, def_pos, Z0tab, Z, cbuf);

  // ---- transformer layers (chunked; arena reused for activations)
  for (int l = 0; l < 4; ++l) {
    for (int c = 0; c < NCH; ++c) {                    // attention sub-block
      const int r0 = c * Mc;
      float* Zc = Z + (size_t)r0 * 512;
      bf16* Z1c  = (bf16*)arena;
      bf16* QKVc = (bf16*)(arena + (size_t)Mc * 1024);
      bf16* Oc   = (bf16*)(arena + (size_t)Mc * 4096);
      ln_kernel<<<Mc/4, 256, 0, stream>>>(Zc, ln1_g + l*512, ln1_b + l*512, Z1c);
      gemm128<false, false, false, true ><<<dim3(12, Mc/128), 256, 0, stream>>>(Z1c, WqkvT + (size_t)l * 786432, nullptr, nullptr, QKVc, Mc, 1536, 512);
      attn_kernel<<<Mc/5, 256, 0, stream>>>(QKVc, cbuf + r0, bias_B + (size_t)l * 800, Oc);
      gemm128<false, false, true,  false><<<dim3(4, Mc/128),  256, 0, stream>>>(Oc, WoT + (size_t)l * 262144, nullptr, Zc, Zc, Mc, 512, 512);
    }
    for (int c = 0; c < NCH; ++c) {                    // FFN sub-block
      const int r0 = c * Mc;
      float* Zc = Z + (size_t)r0 * 512;
      bf16* Z2c = (bf16*)arena;
      bf16* Hc  = (bf16*)(arena + (size_t)Mc * 1024);
      ln_kernel<<<Mc/4, 256, 0, stream>>>(Zc, ln2_g + l*512, ln2_b + l*512, Z2c);
      gemm128<true,  true,  false, true ><<<dim3(16, Mc/128), 256, 0, stream>>>(Z2c, Wf1T + (size_t)l * 1048576, ffn_b1 + (size_t)l * 2048, nullptr, Hc, Mc, 2048, 512);
      gemm128<false, true,  true,  false><<<dim3(4, Mc/128),  256, 0, stream>>>(Hc, Wf2T + (size_t)l * 1048576, ffn_b2 + (size_t)l * 512, Zc, Zc, Mc, 512, 2048);
    }
  }

  // ---- head
  mean_kernel<<<4096, 256, 0, stream>>>(Z, zmean);
  gemm128<true, true, false, true><<<dim3(4, 64), 256, 0, stream>>>(zmean, Wh1T, head_b1, nullptr, hh, 8192, 512, 512);
  head2_kernel<<<2048, 256, 0, stream>>>(hh, head_W2, head_b2, (float*)d_out);
}

// Round 10
// 4755.654 us; speedup vs baseline: 1.6672x; 1.0757x over previous
//
#include <hip/hip_runtime.h>
#include <hip/hip_bf16.h>
#include <stdint.h>

typedef __hip_bfloat16 bf16;
typedef __attribute__((ext_vector_type(4))) float f32x4;
typedef __attribute__((ext_vector_type(8))) short short8v;
typedef __attribute__((ext_vector_type(4))) short short4v;

union U8 { short8v v; bf16 h[8]; };
union U4 { short4v v; bf16 h[4]; };

#define DEV static __device__ __forceinline__

DEV bf16 f2bf(float f) { return __float2bfloat16(f); }
DEV float bf2f(bf16 h) { return __bfloat162float(h); }

DEV void async_copy16(bf16* lds, const bf16* g) {
  __builtin_amdgcn_global_load_lds(
      (const __attribute__((address_space(1))) unsigned int*)g,
      (__attribute__((address_space(3))) unsigned int*)lds,
      16, 0, 0);
}

// ---------------------------------------------------------------- GEMM 128x128
// C(M,N) = act( A(M,K)bf16 @ BT(N,K)^T + bias + Cin ), 4 waves, BK=32.
// Double-buffer 2-phase (proven r6/r8): STAGE(t+1) issued BEFORE compute(t).
template<bool RELU, bool BIAS, bool ADDC, bool OBF16>
__global__ __launch_bounds__(256)
void gemm128(const bf16* __restrict__ A, const bf16* __restrict__ BT,
             const float* __restrict__ bias, const float* __restrict__ Cin,
             void* __restrict__ Dout, int M, int N, int K)
{
  __shared__ __align__(16) bf16 lds[16384];   // 2 bufs x (A 4096 + B 4096 elems)
  const int tid = threadIdx.x;
  const int m0 = blockIdx.y * 128, n0 = blockIdx.x * 128;
  const int wid = tid >> 6, lane = tid & 63;
  const int wr = wid >> 1, wc = wid & 1;
  const int r = lane & 15, g = lane >> 4;

  const int srow = tid >> 2;                   // 0..63
  const int scol = (tid & 3) * 8;
  const bf16* a0 = A  + (size_t)(m0 + srow) * K + scol;
  const bf16* a1 = A  + (size_t)(m0 + srow + 64) * K + scol;
  const bf16* b0 = BT + (size_t)(n0 + srow) * K + scol;
  const bf16* b1 = BT + (size_t)(n0 + srow + 64) * K + scol;

  const int NT = K >> 5;

  f32x4 acc[4][4];
  #pragma unroll
  for (int i = 0; i < 4; ++i)
    #pragma unroll
    for (int j = 0; j < 4; ++j) acc[i][j] = (f32x4){0.f, 0.f, 0.f, 0.f};

  auto STAGE = [&](int t, int buf) {           // 4 x 16B per thread
    bf16* dst = &lds[buf * 8192];
    const int kt = t << 5;
    async_copy16(dst +         tid * 8, a0 + kt);
    async_copy16(dst + 2048 +  tid * 8, a1 + kt);
    async_copy16(dst + 4096 +  tid * 8, b0 + kt);
    async_copy16(dst + 6144 +  tid * 8, b1 + kt);
  };

  STAGE(0, 0);
  __syncthreads();
  int cur = 0;
  for (int t = 0; t < NT; ++t) {
    if (t + 1 < NT) STAGE(t + 1, cur ^ 1);     // in flight during compute below

    const bf16* Ab = &lds[cur * 8192];
    const bf16* Bb = Ab + 4096;
    short8v af[4], bfr[4];
    #pragma unroll
    for (int mi = 0; mi < 4; ++mi)
      af[mi] = *(const short8v*)&Ab[(wr*64 + mi*16 + r) * 32 + g*8];
    #pragma unroll
    for (int ni = 0; ni < 4; ++ni)
      bfr[ni] = *(const short8v*)&Bb[(wc*64 + ni*16 + r) * 32 + g*8];

    __builtin_amdgcn_s_setprio(1);
    #pragma unroll
    for (int mi = 0; mi < 4; ++mi)
      #pragma unroll
      for (int ni = 0; ni < 4; ++ni)
        acc[mi][ni] = __builtin_amdgcn_mfma_f32_16x16x32_bf16(af[mi], bfr[ni], acc[mi][ni], 0, 0, 0);
    __builtin_amdgcn_s_setprio(0);

    __syncthreads();                           // next tile landed; reads done
    cur ^= 1;
  }

  const int mbase = m0 + wr*64;
  const int nbase = n0 + wc*64;
  #pragma unroll
  for (int ni = 0; ni < 4; ++ni) {
    const int col = nbase + ni*16 + r;
    const float bv = BIAS ? bias[col] : 0.f;
    #pragma unroll
    for (int mi = 0; mi < 4; ++mi) {
      #pragma unroll
      for (int b4 = 0; b4 < 4; ++b4) {
        const int row = mbase + mi*16 + g*4 + b4;
        float v = acc[mi][ni][b4] + bv;
        if (ADDC) v += Cin[(size_t)row * N + col];
        if (RELU) v = fmaxf(v, 0.f);
        if (OBF16) ((bf16*)Dout)[(size_t)row * N + col] = f2bf(v);
        else       ((float*)Dout)[(size_t)row * N + col] = v;
      }
    }
  }
}

// ---------------------------------------------------------------- weights: W(K,N) f32 -> WT(N,K) bf16
__global__ __launch_bounds__(256)
void transpose_w(const float* __restrict__ W, bf16* __restrict__ WT, int K, int N)
{
  __shared__ float tl[32][33];
  const int n0 = blockIdx.x * 32, k0 = blockIdx.y * 32;
  const int r = threadIdx.x >> 5, c = threadIdx.x & 31;
  #pragma unroll
  for (int rr = r; rr < 32; rr += 8) tl[rr][c] = W[(size_t)(k0 + rr) * N + n0 + c];
  __syncthreads();
  #pragma unroll
  for (int rr = r; rr < 32; rr += 8) WT[(size_t)(n0 + rr) * K + k0 + c] = f2bf(tl[c][rr]);
}

// ---------------------------------------------------------------- pad pemb chunk: rows [p0, p0+1280)
__global__ __launch_bounds__(128)
void pad_pemb(const float* __restrict__ pemb, bf16* __restrict__ Apad, int p0)
{
  const int lrow = blockIdx.x;
  const int grow = p0 + lrow;
  const int c = threadIdx.x * 4;
  U4 u;
  if (grow < 5000) {
    f32x4 v = *(const f32x4*)(pemb + (size_t)grow * 512 + c);
    u.h[0]=f2bf(v[0]); u.h[1]=f2bf(v[1]); u.h[2]=f2bf(v[2]); u.h[3]=f2bf(v[3]);
  } else {
    u.v = (short4v){0,0,0,0};
  }
  *(short4v*)(Apad + (size_t)lrow * 512 + c) = u.v;
}

// ---------------------------------------------------------------- pad remb -> Rpad (128x512 bf16)
__global__ __launch_bounds__(128)
void pad_remb(const float* __restrict__ remb, bf16* __restrict__ Rpad)
{
  const int row = blockIdx.x;
  const int c = threadIdx.x * 4;
  U4 u;
  if (row < 2) {
    f32x4 v = *(const f32x4*)(remb + (size_t)row * 512 + c);
    u.h[0]=f2bf(v[0]); u.h[1]=f2bf(v[1]); u.h[2]=f2bf(v[2]); u.h[3]=f2bf(v[3]);
  } else {
    u.v = (short4v){0,0,0,0};
  }
  *(short4v*)(Rpad + (size_t)row * 512 + c) = u.v;
}

// ---------------------------------------------------------------- H1 chunk: relu(PW1_c[p] + RW1[role])
__global__ __launch_bounds__(256)
void h1tab_kernel(const bf16* __restrict__ PW1c, const float* __restrict__ RW1,
                  bf16* __restrict__ H1c)
{
  const int row = blockIdx.x;            // 0..2559 : p_local*2+role
  const int p = row >> 1, role = row & 1;
  const int c = threadIdx.x * 4;
  U4 a; a.v = *(const short4v*)(PW1c + (size_t)p * 1024 + c);
  f32x4 rv = *(const f32x4*)(RW1 + (size_t)role * 1024 + c);
  U4 o;
  #pragma unroll
  for (int j = 0; j < 4; ++j) o.h[j] = f2bf(fmaxf(bf2f(a.h[j]) + rv[j], 0.f));
  *(short4v*)(H1c + (size_t)row * 1024 + c) = o.v;
}

// ---------------------------------------------------------------- Z0 gather: Z[row] = f32(Z0tab[pid*2+role]); cbuf
__global__ __launch_bounds__(128)
void z0_gather(const int* __restrict__ off_ids, const int* __restrict__ def_ids,
               const int* __restrict__ off_pos, const int* __restrict__ def_pos,
               const bf16* __restrict__ Z0tab, float* __restrict__ Z,
               int* __restrict__ cbuf)
{
  const int row = blockIdx.x;            // 0..81919
  const int b = row / 10, t = row % 10;
  int pid, pos, role;
  if (t < 5) { pid = off_ids[b*5 + t];   pos = off_pos[b*5 + t];   role = 0; }
  else       { pid = def_ids[b*5 + t-5]; pos = def_pos[b*5 + t-5]; role = 1; }
  if (threadIdx.x == 0) cbuf[row] = role * 5 + pos;
  const int c = threadIdx.x * 4;
  U4 u; u.v = *(const short4v*)(Z0tab + (size_t)(pid * 2 + role) * 512 + c);
  f32x4 v;
  #pragma unroll
  for (int j = 0; j < 4; ++j) v[j] = bf2f(u.h[j]);
  *(f32x4*)(Z + (size_t)row * 512 + c) = v;
}

// ---------------------------------------------------------------- LayerNorm rows of 512, f32 in -> bf16 out
__global__ __launch_bounds__(256)
void ln_kernel(const float* __restrict__ Zin, const float* __restrict__ gam,
               const float* __restrict__ bet, bf16* __restrict__ outp)
{
  const int w = threadIdx.x >> 6, lane = threadIdx.x & 63;
  const size_t row = (size_t)blockIdx.x * 4 + w;
  const float* zp = Zin + row * 512 + lane * 8;
  f32x4 v0 = *(const f32x4*)zp;
  f32x4 v1 = *(const f32x4*)(zp + 4);
  float s = 0.f, ss = 0.f;
  #pragma unroll
  for (int j = 0; j < 4; ++j) { s += v0[j]; ss += v0[j]*v0[j]; }
  #pragma unroll
  for (int j = 0; j < 4; ++j) { s += v1[j]; ss += v1[j]*v1[j]; }
  for (int d0 = 1; d0 < 64; d0 <<= 1) { s += __shfl_xor(s, d0); ss += __shfl_xor(ss, d0); }
  const float mu = s * (1.f/512.f);
  const float rstd = rsqrtf(ss * (1.f/512.f) - mu*mu + 1e-5f);
  const float* gp = gam + lane * 8;
  const float* bp = bet + lane * 8;
  f32x4 g0 = *(const f32x4*)gp, g1 = *(const f32x4*)(gp + 4);
  f32x4 b0 = *(const f32x4*)bp, b1 = *(const f32x4*)(bp + 4);
  U8 u;
  #pragma unroll
  for (int j = 0; j < 4; ++j) u.h[j]     = f2bf((v0[j]-mu)*rstd*g0[j] + b0[j]);
  #pragma unroll
  for (int j = 0; j < 4; ++j) u.h[4 + j] = f2bf((v1[j]-mu)*rstd*g1[j] + b1[j]);
  *(short8v*)(outp + row * 512 + lane * 8) = u.v;
}

// ---------------------------------------------------------------- attention: one wave per (local b, h)
__global__ __launch_bounds__(256)
void attn_kernel(const bf16* __restrict__ qkv, const int* __restrict__ cbuf,
                 const float* __restrict__ biasL, bf16* __restrict__ O)
{
  __shared__ __align__(16) bf16 Plds[4][256];
  __shared__ __align__(16) bf16 Vt[4][1024];
  const int w = threadIdx.x >> 6, lane = threadIdx.x & 63;
  const int wv = blockIdx.x * 4 + w;
  const int b = wv >> 3, h = wv & 7;
  const int r = lane & 15, g = lane >> 4;
  const bf16* base = qkv + (size_t)b * 15360;
  const bool rv = r < 10;
  const short8v z8 = {0,0,0,0,0,0,0,0};

  short8v aq0 = z8, aq1 = z8, bk0 = z8, bk1 = z8;
  if (rv) {
    const bf16* qp = base + (size_t)r * 1536 + h * 64 + g * 8;
    aq0 = *(const short8v*)qp;
    aq1 = *(const short8v*)(qp + 32);
    bk0 = *(const short8v*)(qp + 512);
    bk1 = *(const short8v*)(qp + 544);
  }
  f32x4 s = {0.f, 0.f, 0.f, 0.f};
  s = __builtin_amdgcn_mfma_f32_16x16x32_bf16(aq0, bk0, s, 0, 0, 0);
  s = __builtin_amdgcn_mfma_f32_16x16x32_bf16(aq1, bk1, s, 0, 0, 0);

  bf16* V = Vt[w];
  {
    const int j1 = lane >> 3, d0 = (lane & 7) * 8;
    U8 uv; uv.v = *(const short8v*)(base + (size_t)j1 * 1536 + 1024 + h * 64 + d0);
    #pragma unroll
    for (int m2 = 0; m2 < 8; ++m2) V[(d0 + m2) * 16 + j1] = uv.h[m2];
    const int j2 = 8 + j1;
    U8 uv2; uv2.v = z8;
    if (j2 < 10) uv2.v = *(const short8v*)(base + (size_t)j2 * 1536 + 1024 + h * 64 + d0);
    #pragma unroll
    for (int m2 = 0; m2 < 8; ++m2) V[(d0 + m2) * 16 + j2] = uv2.h[m2];
  }

  const int cj = rv ? cbuf[b * 10 + r] : 0;
  float sv[4];
  #pragma unroll
  for (int q4 = 0; q4 < 4; ++q4) {
    const int i = g * 4 + q4;
    float val = s[q4] * 0.125f;
    if (rv && i < 10) val += biasL[h * 100 + cbuf[b * 10 + i] * 10 + cj];
    if (!rv) val = -1e30f;
    sv[q4] = val;
  }
  float mx[4];
  #pragma unroll
  for (int q4 = 0; q4 < 4; ++q4) mx[q4] = sv[q4];
  for (int d0 = 1; d0 < 16; d0 <<= 1) {
    #pragma unroll
    for (int q4 = 0; q4 < 4; ++q4) mx[q4] = fmaxf(mx[q4], __shfl_xor(mx[q4], d0));
  }
  float pe[4], sm[4];
  #pragma unroll
  for (int q4 = 0; q4 < 4; ++q4) { pe[q4] = __expf(sv[q4] - mx[q4]); sm[q4] = pe[q4]; }
  for (int d0 = 1; d0 < 16; d0 <<= 1) {
    #pragma unroll
    for (int q4 = 0; q4 < 4; ++q4) sm[q4] += __shfl_xor(sm[q4], d0);
  }

  bf16* P = Plds[w];
  #pragma unroll
  for (int q4 = 0; q4 < 4; ++q4) P[(g * 4 + q4) * 16 + r] = f2bf(pe[q4] / sm[q4]);

  short8v pa = z8;
  if (g < 2) pa = *(const short8v*)&P[r * 16 + g * 8];
  #pragma unroll
  for (int db = 0; db < 4; ++db) {
    short8v bv = z8;
    if (g < 2) bv = *(const short8v*)&V[(db * 16 + r) * 16 + g * 8];
    f32x4 o = {0.f, 0.f, 0.f, 0.f};
    o = __builtin_amdgcn_mfma_f32_16x16x32_bf16(pa, bv, o, 0, 0, 0);
    #pragma unroll
    for (int q4 = 0; q4 < 4; ++q4) {
      const int i = g * 4 + q4;
      if (i < 10) O[(size_t)(b * 10 + i) * 512 + h * 64 + db * 16 + r] = f2bf(o[q4]);
    }
  }
}

// ---------------------------------------------------------------- token mean
__global__ __launch_bounds__(256)
void mean_kernel(const float* __restrict__ Zin, bf16* __restrict__ zm)
{
  const int idx = blockIdx.x * 256 + threadIdx.x;
  const int b = idx >> 7, d4 = (idx & 127) << 2;
  const float* p = Zin + (size_t)b * 5120 + d4;
  f32x4 a = {0.f, 0.f, 0.f, 0.f};
  #pragma unroll
  for (int i = 0; i < 10; ++i) a += *(const f32x4*)(p + (size_t)i * 512);
  a *= 0.1f;
  U4 u;
  #pragma unroll
  for (int j = 0; j < 4; ++j) u.h[j] = f2bf(a[j]);
  *(short4v*)(zm + (size_t)b * 512 + d4) = u.v;
}

// ---------------------------------------------------------------- head2
__global__ __launch_bounds__(256)
void head2_kernel(const bf16* __restrict__ hh, const float* __restrict__ W2,
                  const float* __restrict__ b2, float* __restrict__ out)
{
  const int w = threadIdx.x >> 6, lane = threadIdx.x & 63;
  const int b = blockIdx.x * 4 + w;
  U8 u; u.v = *(const short8v*)(hh + (size_t)b * 512 + lane * 8);
  float p[5] = {0.f, 0.f, 0.f, 0.f, 0.f};
  #pragma unroll
  for (int j = 0; j < 8; ++j) {
    const float hf = bf2f(u.h[j]);
    const float* wp = W2 + (size_t)(lane * 8 + j) * 5;
    #pragma unroll
    for (int c = 0; c < 5; ++c) p[c] += hf * wp[c];
  }
  for (int d0 = 1; d0 < 64; d0 <<= 1) {
    #pragma unroll
    for (int c = 0; c < 5; ++c) p[c] += __shfl_xor(p[c], d0);
  }
  if (lane == 0) {
    float* op = out + (size_t)b * 5;
    #pragma unroll
    for (int c = 0; c < 5; ++c) op[c] = p[c] + b2[c];
  }
}

// ----------------------------------------------------------------
extern "C" void kernel_launch(void* const* d_in, const int* in_sizes, int n_in,
                              void* d_out, int out_size, void* d_ws, size_t ws_size,
                              hipStream_t stream)
{
  const int*   off_ids = (const int*)d_in[0];
  const int*   def_ids = (const int*)d_in[1];
  const int*   off_pos = (const int*)d_in[2];
  const int*   def_pos = (const int*)d_in[3];
  const float* pemb    = (const float*)d_in[4];
  const float* remb    = (const float*)d_in[5];
  const float* proj_W1 = (const float*)d_in[6];
  const float* proj_b1 = (const float*)d_in[7];
  const float* proj_W2 = (const float*)d_in[8];
  const float* proj_b2 = (const float*)d_in[9];
  const float* ln1_g   = (const float*)d_in[10];
  const float* ln1_b   = (const float*)d_in[11];
  const float* Wq      = (const float*)d_in[12];
  const float* Wk      = (const float*)d_in[13];
  const float* Wv      = (const float*)d_in[14];
  const float* Wo      = (const float*)d_in[15];
  const float* bias_B  = (const float*)d_in[16];
  const float* ln2_g   = (const float*)d_in[17];
  const float* ln2_b   = (const float*)d_in[18];
  const float* ffn_W1  = (const float*)d_in[19];
  const float* ffn_b1  = (const float*)d_in[20];
  const float* ffn_W2  = (const float*)d_in[21];
  const float* ffn_b2  = (const float*)d_in[22];
  const float* head_W1 = (const float*)d_in[23];
  const float* head_b1 = (const float*)d_in[24];
  const float* head_W2 = (const float*)d_in[25];
  const float* head_b2 = (const float*)d_in[26];
  (void)in_sizes; (void)n_in; (void)out_size;

  char* ws = (char*)d_ws;
  size_t off = 0;
  auto take = [&](size_t bytes) -> char* {
    char* p = ws + off; off += (bytes + 255) & ~(size_t)255; return p;
  };

  // ---- fixed allocations (~166.3 MiB)
  float* Z    = (float*)take(81920ull * 512 * 4);   // residual f32 (160MiB)
  bf16*  WJ   = (bf16*)take(3145728ull * 2);        // 6MiB per-layer weight buffer (JIT)
  int*   cbuf = (int*)take(81920ull * 4);

  // ---- adaptive chunk sizes
  const size_t fixed_end = off;
  const size_t avail = (ws_size > fixed_end + (1u << 20)) ? (ws_size - fixed_end - (1u << 20)) : 0;
  int McA = 81920;                                   // attn phase: 4KB/row (Z1|O + QKV)
  while (McA > 2560 && (size_t)McA * 4096 > avail) McA >>= 1;
  int McF = 81920;                                   // ffn phase: 5KB/row (Z2 + H)
  while (McF > 2560 && (size_t)McF * 5120 > avail) McF >>= 1;
  char* arena = ws + fixed_end;

  // per-layer weight views inside WJ (elems)
  bf16* WqkvT_l = WJ;                 // 1536 x 512
  bf16* WoT_l   = WJ +  786432;       //  512 x 512
  bf16* Wf1T_l  = WJ + 1048576;       // 2048 x 512
  bf16* Wf2T_l  = WJ + 2097152;       //  512 x 2048

  auto T = [&](const float* W, bf16* WT, int K, int N) {
    transpose_w<<<dim3(N / 32, K / 32), 256, 0, stream>>>(W, WT, K, N);
  };

  // ---- prologue: Z0tab[(pid,role)] replaces the proj MLP on all 81920 rows
  // prologue weights live in WJ (dead before layer 0's JIT transposes)
  bf16* W1topT = WJ;                  // 1024 x 512
  bf16* W1botT = WJ +  524288;        // 1024 x 512
  bf16* Wp2T   = WJ + 1048576;        //  512 x 1024
  // prologue scratch in arena (dead before layer loop)
  char* tb = arena;
  auto ttake = [&](size_t bytes) -> char* {
    char* p = tb; tb += (bytes + 255) & ~(size_t)255; return p;
  };
  bf16*  Z0tab = (bf16*)ttake(10240ull * 512 * 2);  // 10MiB
  bf16*  Rpad  = (bf16*)ttake(128ull * 512 * 2);
  float* RW1   = (float*)ttake(128ull * 1024 * 4);
  bf16*  ApadC = (bf16*)ttake(1280ull * 512 * 2);
  bf16*  PW1C  = (bf16*)ttake(1280ull * 1024 * 2);
  bf16*  H1C   = (bf16*)ttake(2560ull * 1024 * 2);

  T(proj_W1,               W1topT, 512, 1024);      // W1 rows 0..511   (e half)
  T(proj_W1 + 512ull*1024, W1botT, 512, 1024);      // W1 rows 512..1023 (r half)
  T(proj_W2, Wp2T, 1024, 512);
  pad_remb<<<128, 128, 0, stream>>>(remb, Rpad);
  gemm128<false, true, false, false><<<dim3(8, 1), 256, 0, stream>>>(Rpad, W1botT, proj_b1, nullptr, RW1, 128, 1024, 512);
  for (int pc = 0; pc < 4; ++pc) {                  // 1280 players / chunk
    pad_pemb<<<1280, 128, 0, stream>>>(pemb, ApadC, pc * 1280);
    gemm128<false, false, false, true ><<<dim3(8, 10), 256, 0, stream>>>(ApadC, W1topT, nullptr, nullptr, PW1C, 1280, 1024, 512);
    h1tab_kernel<<<2560, 256, 0, stream>>>(PW1C, RW1, H1C);
    gemm128<false, true,  false, true ><<<dim3(4, 20), 256, 0, stream>>>(H1C, Wp2T, proj_b2, nullptr, Z0tab + (size_t)pc * 2560 * 512, 2560, 512, 1024);
  }
  z0_gather<<<81920, 128, 0, stream>>>(off_ids, def_ids, off_pos, def_pos, Z0tab, Z, cbuf);

  // ---- transformer layers (JIT weight transposes; arena reused for activations)
  const int NCA = 81920 / McA, NCF = 81920 / McF;
  for (int l = 0; l < 4; ++l) {
    T(Wq + (size_t)l * 262144, WqkvT_l,          512, 512);
    T(Wk + (size_t)l * 262144, WqkvT_l + 262144, 512, 512);
    T(Wv + (size_t)l * 262144, WqkvT_l + 524288, 512, 512);
    T(Wo + (size_t)l * 262144, WoT_l,            512, 512);
    T(ffn_W1 + (size_t)l * 1048576, Wf1T_l, 512, 2048);
    T(ffn_W2 + (size_t)l * 1048576, Wf2T_l, 2048, 512);

    for (int c = 0; c < NCA; ++c) {                 // attention sub-block (4KB/row)
      const int r0 = c * McA;
      float* Zc = Z + (size_t)r0 * 512;
      bf16* Z1c  = (bf16*)arena;                    // McA x 512 (Z1, later reused as O)
      bf16* QKVc = (bf16*)(arena + (size_t)McA * 1024); // McA x 1536
      ln_kernel<<<McA/4, 256, 0, stream>>>(Zc, ln1_g + l*512, ln1_b + l*512, Z1c);
      gemm128<false, false, false, true ><<<dim3(12, McA/128), 256, 0, stream>>>(Z1c, WqkvT_l, nullptr, nullptr, QKVc, McA, 1536, 512);
      attn_kernel<<<McA/5, 256, 0, stream>>>(QKVc, cbuf + r0, bias_B + (size_t)l * 800, Z1c); // O overwrites Z1 (dead)
      gemm128<false, false, true,  false><<<dim3(4, McA/128),  256, 0, stream>>>(Z1c, WoT_l, nullptr, Zc, Zc, McA, 512, 512);
    }
    for (int c = 0; c < NCF; ++c) {                 // FFN sub-block (5KB/row)
      const int r0 = c * McF;
      float* Zc = Z + (size_t)r0 * 512;
      bf16* Z2c = (bf16*)arena;                     // McF x 512
      bf16* Hc  = (bf16*)(arena + (size_t)McF * 1024); // McF x 2048
      ln_kernel<<<McF/4, 256, 0, stream>>>(Zc, ln2_g + l*512, ln2_b + l*512, Z2c);
      gemm128<true,  true,  false, true ><<<dim3(16, McF/128), 256, 0, stream>>>(Z2c, Wf1T_l, ffn_b1 + (size_t)l * 2048, nullptr, Hc, McF, 2048, 512);
      gemm128<false, true,  true,  false><<<dim3(4, McF/128),  256, 0, stream>>>(Hc, Wf2T_l, ffn_b2 + (size_t)l * 512, Zc, Zc, McF, 512, 2048);
    }
  }

  // ---- head (zmean/hh overlay arena; head_W1 re-transposed into WJ)
  bf16* zmean = (bf16*)arena;                       // 8192 x 512 bf16
  bf16* hh    = (bf16*)(arena + 8388608ull);        // 8192 x 512 bf16
  bf16* Wh1T  = WJ;                                 // 512 x 512
  T(head_W1, Wh1T, 512, 512);
  mean_kernel<<<4096, 256, 0, stream>>>(Z, zmean);
  gemm128<true, true, false, true><<<dim3(4, 64), 256, 0, stream>>>(zmean, Wh1T, head_b1, nullptr, hh, 8192, 512, 512);
  head2_kernel<<<2048, 256, 0, stream>>>(hh, head_W2, head_b2, (float*)d_out);
}

// Round 11
// 4467.250 us; speedup vs baseline: 1.7748x; 1.0646x over previous
//
#include <hip/hip_runtime.h>
#include <hip/hip_bf16.h>
#include <stdint.h>

typedef __hip_bfloat16 bf16;
typedef __attribute__((ext_vector_type(4))) float f32x4;
typedef __attribute__((ext_vector_type(8))) short short8v;
typedef __attribute__((ext_vector_type(4))) short short4v;

union U8 { short8v v; bf16 h[8]; };
union U4 { short4v v; bf16 h[4]; };

#define DEV static __device__ __forceinline__

DEV bf16 f2bf(float f) { return __float2bfloat16(f); }
DEV float bf2f(bf16 h) { return __bfloat162float(h); }

DEV void async_copy16(bf16* lds, const bf16* g) {
  __builtin_amdgcn_global_load_lds(
      (const __attribute__((address_space(1))) unsigned int*)g,
      (__attribute__((address_space(3))) unsigned int*)lds,
      16, 0, 0);
}

// ---------------------------------------------------------------- GEMM 128x128
// C(M,N) = act( A(M,K)bf16 @ BT(N,K)^T + bias + Cin ), 4 waves, BK=32.
// Double-buffer 2-phase (proven r6/r8) + T1 bijective XCD-chunked swizzle:
// each XCD gets a contiguous tile range -> A-panels fetched once, L2-local.
template<bool RELU, bool BIAS, bool ADDC, bool OBF16>
__global__ __launch_bounds__(256)
void gemm128(const bf16* __restrict__ A, const bf16* __restrict__ BT,
             const float* __restrict__ bias, const float* __restrict__ Cin,
             void* __restrict__ Dout, int M, int N, int K)
{
  __shared__ __align__(16) bf16 lds[16384];   // 2 bufs x (A 4096 + B 4096 elems)
  const int tid = threadIdx.x;

  // T1: bid -> swz (m204 bijective chunked form; HW round-robins bid%8 over XCDs)
  const int nwg = gridDim.x * gridDim.y;
  const int bid = blockIdx.y * gridDim.x + blockIdx.x;
  const int q = nwg >> 3, rr = nwg & 7;
  const int xcd = bid & 7, idx = bid >> 3;
  const int swz = (xcd < rr ? xcd * (q + 1) : rr * (q + 1) + (xcd - rr) * q) + idx;
  const int m0 = (swz / gridDim.x) * 128;
  const int n0 = (swz % gridDim.x) * 128;

  const int wid = tid >> 6, lane = tid & 63;
  const int wr = wid >> 1, wc = wid & 1;
  const int r = lane & 15, g = lane >> 4;

  const int srow = tid >> 2;                   // 0..63
  const int scol = (tid & 3) * 8;
  const bf16* a0 = A  + (size_t)(m0 + srow) * K + scol;
  const bf16* a1 = A  + (size_t)(m0 + srow + 64) * K + scol;
  const bf16* b0 = BT + (size_t)(n0 + srow) * K + scol;
  const bf16* b1 = BT + (size_t)(n0 + srow + 64) * K + scol;

  const int NT = K >> 5;

  f32x4 acc[4][4];
  #pragma unroll
  for (int i = 0; i < 4; ++i)
    #pragma unroll
    for (int j = 0; j < 4; ++j) acc[i][j] = (f32x4){0.f, 0.f, 0.f, 0.f};

  auto STAGE = [&](int t, int buf) {           // 4 x 16B per thread
    bf16* dst = &lds[buf * 8192];
    const int kt = t << 5;
    async_copy16(dst +         tid * 8, a0 + kt);
    async_copy16(dst + 2048 +  tid * 8, a1 + kt);
    async_copy16(dst + 4096 +  tid * 8, b0 + kt);
    async_copy16(dst + 6144 +  tid * 8, b1 + kt);
  };

  STAGE(0, 0);
  __syncthreads();
  int cur = 0;
  for (int t = 0; t < NT; ++t) {
    if (t + 1 < NT) STAGE(t + 1, cur ^ 1);     // in flight during compute below

    const bf16* Ab = &lds[cur * 8192];
    const bf16* Bb = Ab + 4096;
    short8v af[4], bfr[4];
    #pragma unroll
    for (int mi = 0; mi < 4; ++mi)
      af[mi] = *(const short8v*)&Ab[(wr*64 + mi*16 + r) * 32 + g*8];
    #pragma unroll
    for (int ni = 0; ni < 4; ++ni)
      bfr[ni] = *(const short8v*)&Bb[(wc*64 + ni*16 + r) * 32 + g*8];

    __builtin_amdgcn_s_setprio(1);
    #pragma unroll
    for (int mi = 0; mi < 4; ++mi)
      #pragma unroll
      for (int ni = 0; ni < 4; ++ni)
        acc[mi][ni] = __builtin_amdgcn_mfma_f32_16x16x32_bf16(af[mi], bfr[ni], acc[mi][ni], 0, 0, 0);
    __builtin_amdgcn_s_setprio(0);

    __syncthreads();                           // next tile landed; reads done
    cur ^= 1;
  }

  const int mbase = m0 + wr*64;
  const int nbase = n0 + wc*64;
  #pragma unroll
  for (int ni = 0; ni < 4; ++ni) {
    const int col = nbase + ni*16 + r;
    const float bv = BIAS ? bias[col] : 0.f;
    #pragma unroll
    for (int mi = 0; mi < 4; ++mi) {
      #pragma unroll
      for (int b4 = 0; b4 < 4; ++b4) {
        const int row = mbase + mi*16 + g*4 + b4;
        float v = acc[mi][ni][b4] + bv;
        if (ADDC) v += Cin[(size_t)row * N + col];
        if (RELU) v = fmaxf(v, 0.f);
        if (OBF16) ((bf16*)Dout)[(size_t)row * N + col] = f2bf(v);
        else       ((float*)Dout)[(size_t)row * N + col] = v;
      }
    }
  }
}

// ---------------------------------------------------------------- weights: W(K,N) f32 -> WT(N,K) bf16
__global__ __launch_bounds__(256)
void transpose_w(const float* __restrict__ W, bf16* __restrict__ WT, int K, int N)
{
  __shared__ float tl[32][33];
  const int n0 = blockIdx.x * 32, k0 = blockIdx.y * 32;
  const int r = threadIdx.x >> 5, c = threadIdx.x & 31;
  #pragma unroll
  for (int rr = r; rr < 32; rr += 8) tl[rr][c] = W[(size_t)(k0 + rr) * N + n0 + c];
  __syncthreads();
  #pragma unroll
  for (int rr = r; rr < 32; rr += 8) WT[(size_t)(n0 + rr) * K + k0 + c] = f2bf(tl[c][rr]);
}

// ---------------------------------------------------------------- pad pemb chunk: rows [p0, p0+1280)
__global__ __launch_bounds__(128)
void pad_pemb(const float* __restrict__ pemb, bf16* __restrict__ Apad, int p0)
{
  const int lrow = blockIdx.x;
  const int grow = p0 + lrow;
  const int c = threadIdx.x * 4;
  U4 u;
  if (grow < 5000) {
    f32x4 v = *(const f32x4*)(pemb + (size_t)grow * 512 + c);
    u.h[0]=f2bf(v[0]); u.h[1]=f2bf(v[1]); u.h[2]=f2bf(v[2]); u.h[3]=f2bf(v[3]);
  } else {
    u.v = (short4v){0,0,0,0};
  }
  *(short4v*)(Apad + (size_t)lrow * 512 + c) = u.v;
}

// ---------------------------------------------------------------- pad remb -> Rpad (128x512 bf16)
__global__ __launch_bounds__(128)
void pad_remb(const float* __restrict__ remb, bf16* __restrict__ Rpad)
{
  const int row = blockIdx.x;
  const int c = threadIdx.x * 4;
  U4 u;
  if (row < 2) {
    f32x4 v = *(const f32x4*)(remb + (size_t)row * 512 + c);
    u.h[0]=f2bf(v[0]); u.h[1]=f2bf(v[1]); u.h[2]=f2bf(v[2]); u.h[3]=f2bf(v[3]);
  } else {
    u.v = (short4v){0,0,0,0};
  }
  *(short4v*)(Rpad + (size_t)row * 512 + c) = u.v;
}

// ---------------------------------------------------------------- H1 chunk: relu(PW1_c[p] + RW1[role])
__global__ __launch_bounds__(256)
void h1tab_kernel(const bf16* __restrict__ PW1c, const float* __restrict__ RW1,
                  bf16* __restrict__ H1c)
{
  const int row = blockIdx.x;            // 0..2559 : p_local*2+role
  const int p = row >> 1, role = row & 1;
  const int c = threadIdx.x * 4;
  U4 a; a.v = *(const short4v*)(PW1c + (size_t)p * 1024 + c);
  f32x4 rv = *(const f32x4*)(RW1 + (size_t)role * 1024 + c);
  U4 o;
  #pragma unroll
  for (int j = 0; j < 4; ++j) o.h[j] = f2bf(fmaxf(bf2f(a.h[j]) + rv[j], 0.f));
  *(short4v*)(H1c + (size_t)row * 1024 + c) = o.v;
}

// ---------------------------------------------------------------- Z0 gather: Z[row] = f32(Z0tab[pid*2+role]); cbuf
__global__ __launch_bounds__(128)
void z0_gather(const int* __restrict__ off_ids, const int* __restrict__ def_ids,
               const int* __restrict__ off_pos, const int* __restrict__ def_pos,
               const bf16* __restrict__ Z0tab, float* __restrict__ Z,
               int* __restrict__ cbuf)
{
  const int row = blockIdx.x;            // 0..81919
  const int b = row / 10, t = row % 10;
  int pid, pos, role;
  if (t < 5) { pid = off_ids[b*5 + t];   pos = off_pos[b*5 + t];   role = 0; }
  else       { pid = def_ids[b*5 + t-5]; pos = def_pos[b*5 + t-5]; role = 1; }
  if (threadIdx.x == 0) cbuf[row] = role * 5 + pos;
  const int c = threadIdx.x * 4;
  U4 u; u.v = *(const short4v*)(Z0tab + (size_t)(pid * 2 + role) * 512 + c);
  f32x4 v;
  #pragma unroll
  for (int j = 0; j < 4; ++j) v[j] = bf2f(u.h[j]);
  *(f32x4*)(Z + (size_t)row * 512 + c) = v;
}

// ---------------------------------------------------------------- LayerNorm rows of 512, f32 in -> bf16 out
__global__ __launch_bounds__(256)
void ln_kernel(const float* __restrict__ Zin, const float* __restrict__ gam,
               const float* __restrict__ bet, bf16* __restrict__ outp)
{
  const int w = threadIdx.x >> 6, lane = threadIdx.x & 63;
  const size_t row = (size_t)blockIdx.x * 4 + w;
  const float* zp = Zin + row * 512 + lane * 8;
  f32x4 v0 = *(const f32x4*)zp;
  f32x4 v1 = *(const f32x4*)(zp + 4);
  float s = 0.f, ss = 0.f;
  #pragma unroll
  for (int j = 0; j < 4; ++j) { s += v0[j]; ss += v0[j]*v0[j]; }
  #pragma unroll
  for (int j = 0; j < 4; ++j) { s += v1[j]; ss += v1[j]*v1[j]; }
  for (int d0 = 1; d0 < 64; d0 <<= 1) { s += __shfl_xor(s, d0); ss += __shfl_xor(ss, d0); }
  const float mu = s * (1.f/512.f);
  const float rstd = rsqrtf(ss * (1.f/512.f) - mu*mu + 1e-5f);
  const float* gp = gam + lane * 8;
  const float* bp = bet + lane * 8;
  f32x4 g0 = *(const f32x4*)gp, g1 = *(const f32x4*)(gp + 4);
  f32x4 b0 = *(const f32x4*)bp, b1 = *(const f32x4*)(bp + 4);
  U8 u;
  #pragma unroll
  for (int j = 0; j < 4; ++j) u.h[j]     = f2bf((v0[j]-mu)*rstd*g0[j] + b0[j]);
  #pragma unroll
  for (int j = 0; j < 4; ++j) u.h[4 + j] = f2bf((v1[j]-mu)*rstd*g1[j] + b1[j]);
  *(short8v*)(outp + row * 512 + lane * 8) = u.v;
}

// ---------------------------------------------------------------- attention: one wave per (local b, h)
__global__ __launch_bounds__(256)
void attn_kernel(const bf16* __restrict__ qkv, const int* __restrict__ cbuf,
                 const float* __restrict__ biasL, bf16* __restrict__ O)
{
  __shared__ __align__(16) bf16 Plds[4][256];
  __shared__ __align__(16) bf16 Vt[4][1024];
  const int w = threadIdx.x >> 6, lane = threadIdx.x & 63;
  const int wv = blockIdx.x * 4 + w;
  const int b = wv >> 3, h = wv & 7;
  const int r = lane & 15, g = lane >> 4;
  const bf16* base = qkv + (size_t)b * 15360;
  const bool rv = r < 10;
  const short8v z8 = {0,0,0,0,0,0,0,0};

  short8v aq0 = z8, aq1 = z8, bk0 = z8, bk1 = z8;
  if (rv) {
    const bf16* qp = base + (size_t)r * 1536 + h * 64 + g * 8;
    aq0 = *(const short8v*)qp;
    aq1 = *(const short8v*)(qp + 32);
    bk0 = *(const short8v*)(qp + 512);
    bk1 = *(const short8v*)(qp + 544);
  }
  f32x4 s = {0.f, 0.f, 0.f, 0.f};
  s = __builtin_amdgcn_mfma_f32_16x16x32_bf16(aq0, bk0, s, 0, 0, 0);
  s = __builtin_amdgcn_mfma_f32_16x16x32_bf16(aq1, bk1, s, 0, 0, 0);

  bf16* V = Vt[w];
  {
    const int j1 = lane >> 3, d0 = (lane & 7) * 8;
    U8 uv; uv.v = *(const short8v*)(base + (size_t)j1 * 1536 + 1024 + h * 64 + d0);
    #pragma unroll
    for (int m2 = 0; m2 < 8; ++m2) V[(d0 + m2) * 16 + j1] = uv.h[m2];
    const int j2 = 8 + j1;
    U8 uv2; uv2.v = z8;
    if (j2 < 10) uv2.v = *(const short8v*)(base + (size_t)j2 * 1536 + 1024 + h * 64 + d0);
    #pragma unroll
    for (int m2 = 0; m2 < 8; ++m2) V[(d0 + m2) * 16 + j2] = uv2.h[m2];
  }

  const int cj = rv ? cbuf[b * 10 + r] : 0;
  float sv[4];
  #pragma unroll
  for (int q4 = 0; q4 < 4; ++q4) {
    const int i = g * 4 + q4;
    float val = s[q4] * 0.125f;
    if (rv && i < 10) val += biasL[h * 100 + cbuf[b * 10 + i] * 10 + cj];
    if (!rv) val = -1e30f;
    sv[q4] = val;
  }
  float mx[4];
  #pragma unroll
  for (int q4 = 0; q4 < 4; ++q4) mx[q4] = sv[q4];
  for (int d0 = 1; d0 < 16; d0 <<= 1) {
    #pragma unroll
    for (int q4 = 0; q4 < 4; ++q4) mx[q4] = fmaxf(mx[q4], __shfl_xor(mx[q4], d0));
  }
  float pe[4], sm[4];
  #pragma unroll
  for (int q4 = 0; q4 < 4; ++q4) { pe[q4] = __expf(sv[q4] - mx[q4]); sm[q4] = pe[q4]; }
  for (int d0 = 1; d0 < 16; d0 <<= 1) {
    #pragma unroll
    for (int q4 = 0; q4 < 4; ++q4) sm[q4] += __shfl_xor(sm[q4], d0);
  }

  bf16* P = Plds[w];
  #pragma unroll
  for (int q4 = 0; q4 < 4; ++q4) P[(g * 4 + q4) * 16 + r] = f2bf(pe[q4] / sm[q4]);

  short8v pa = z8;
  if (g < 2) pa = *(const short8v*)&P[r * 16 + g * 8];
  #pragma unroll
  for (int db = 0; db < 4; ++db) {
    short8v bv = z8;
    if (g < 2) bv = *(const short8v*)&V[(db * 16 + r) * 16 + g * 8];
    f32x4 o = {0.f, 0.f, 0.f, 0.f};
    o = __builtin_amdgcn_mfma_f32_16x16x32_bf16(pa, bv, o, 0, 0, 0);
    #pragma unroll
    for (int q4 = 0; q4 < 4; ++q4) {
      const int i = g * 4 + q4;
      if (i < 10) O[(size_t)(b * 10 + i) * 512 + h * 64 + db * 16 + r] = f2bf(o[q4]);
    }
  }
}

// ---------------------------------------------------------------- token mean
__global__ __launch_bounds__(256)
void mean_kernel(const float* __restrict__ Zin, bf16* __restrict__ zm)
{
  const int idx = blockIdx.x * 256 + threadIdx.x;
  const int b = idx >> 7, d4 = (idx & 127) << 2;
  const float* p = Zin + (size_t)b * 5120 + d4;
  f32x4 a = {0.f, 0.f, 0.f, 0.f};
  #pragma unroll
  for (int i = 0; i < 10; ++i) a += *(const f32x4*)(p + (size_t)i * 512);
  a *= 0.1f;
  U4 u;
  #pragma unroll
  for (int j = 0; j < 4; ++j) u.h[j] = f2bf(a[j]);
  *(short4v*)(zm + (size_t)b * 512 + d4) = u.v;
}

// ---------------------------------------------------------------- head2
__global__ __launch_bounds__(256)
void head2_kernel(const bf16* __restrict__ hh, const float* __restrict__ W2,
                  const float* __restrict__ b2, float* __restrict__ out)
{
  const int w = threadIdx.x >> 6, lane = threadIdx.x & 63;
  const int b = blockIdx.x * 4 + w;
  U8 u; u.v = *(const short8v*)(hh + (size_t)b * 512 + lane * 8);
  float p[5] = {0.f, 0.f, 0.f, 0.f, 0.f};
  #pragma unroll
  for (int j = 0; j < 8; ++j) {
    const float hf = bf2f(u.h[j]);
    const float* wp = W2 + (size_t)(lane * 8 + j) * 5;
    #pragma unroll
    for (int c = 0; c < 5; ++c) p[c] += hf * wp[c];
  }
  for (int d0 = 1; d0 < 64; d0 <<= 1) {
    #pragma unroll
    for (int c = 0; c < 5; ++c) p[c] += __shfl_xor(p[c], d0);
  }
  if (lane == 0) {
    float* op = out + (size_t)b * 5;
    #pragma unroll
    for (int c = 0; c < 5; ++c) op[c] = p[c] + b2[c];
  }
}

// ----------------------------------------------------------------
extern "C" void kernel_launch(void* const* d_in, const int* in_sizes, int n_in,
                              void* d_out, int out_size, void* d_ws, size_t ws_size,
                              hipStream_t stream)
{
  const int*   off_ids = (const int*)d_in[0];
  const int*   def_ids = (const int*)d_in[1];
  const int*   off_pos = (const int*)d_in[2];
  const int*   def_pos = (const int*)d_in[3];
  const float* pemb    = (const float*)d_in[4];
  const float* remb    = (const float*)d_in[5];
  const float* proj_W1 = (const float*)d_in[6];
  const float* proj_b1 = (const float*)d_in[7];
  const float* proj_W2 = (const float*)d_in[8];
  const float* proj_b2 = (const float*)d_in[9];
  const float* ln1_g   = (const float*)d_in[10];
  const float* ln1_b   = (const float*)d_in[11];
  const float* Wq      = (const float*)d_in[12];
  const float* Wk      = (const float*)d_in[13];
  const float* Wv      = (const float*)d_in[14];
  const float* Wo      = (const float*)d_in[15];
  const float* bias_B  = (const float*)d_in[16];
  const float* ln2_g   = (const float*)d_in[17];
  const float* ln2_b   = (const float*)d_in[18];
  const float* ffn_W1  = (const float*)d_in[19];
  const float* ffn_b1  = (const float*)d_in[20];
  const float* ffn_W2  = (const float*)d_in[21];
  const float* ffn_b2  = (const float*)d_in[22];
  const float* head_W1 = (const float*)d_in[23];
  const float* head_b1 = (const float*)d_in[24];
  const float* head_W2 = (const float*)d_in[25];
  const float* head_b2 = (const float*)d_in[26];
  (void)in_sizes; (void)n_in; (void)out_size;

  char* ws = (char*)d_ws;
  size_t off = 0;
  auto take = [&](size_t bytes) -> char* {
    char* p = ws + off; off += (bytes + 255) & ~(size_t)255; return p;
  };

  // ---- fixed allocations (~166.3 MiB)
  float* Z    = (float*)take(81920ull * 512 * 4);   // residual f32 (160MiB)
  bf16*  WJ   = (bf16*)take(3145728ull * 2);        // 6MiB per-layer weight buffer (JIT)
  int*   cbuf = (int*)take(81920ull * 4);

  // ---- adaptive chunk sizes
  const size_t fixed_end = off;
  const size_t avail = (ws_size > fixed_end + (1u << 20)) ? (ws_size - fixed_end - (1u << 20)) : 0;
  int McA = 81920;                                   // attn phase: 4KB/row (Z1|O + QKV)
  while (McA > 2560 && (size_t)McA * 4096 > avail) McA >>= 1;
  int McF = 81920;                                   // ffn phase: 5KB/row (Z2 + H)
  while (McF > 2560 && (size_t)McF * 5120 > avail) McF >>= 1;
  char* arena = ws + fixed_end;

  // per-layer weight views inside WJ (elems)
  bf16* WqkvT_l = WJ;                 // 1536 x 512
  bf16* WoT_l   = WJ +  786432;       //  512 x 512
  bf16* Wf1T_l  = WJ + 1048576;       // 2048 x 512
  bf16* Wf2T_l  = WJ + 2097152;       //  512 x 2048

  auto T = [&](const float* W, bf16* WT, int K, int N) {
    transpose_w<<<dim3(N / 32, K / 32), 256, 0, stream>>>(W, WT, K, N);
  };

  // ---- prologue: Z0tab[(pid,role)] replaces the proj MLP on all 81920 rows
  // prologue weights live in WJ (dead before layer 0's JIT transposes)
  bf16* W1topT = WJ;                  // 1024 x 512
  bf16* W1botT = WJ +  524288;        // 1024 x 512
  bf16* Wp2T   = WJ + 1048576;        //  512 x 1024
  // prologue scratch in arena (dead before layer loop)
  char* tb = arena;
  auto ttake = [&](size_t bytes) -> char* {
    char* p = tb; tb += (bytes + 255) & ~(size_t)255; return p;
  };
  bf16*  Z0tab = (bf16*)ttake(10240ull * 512 * 2);  // 10MiB
  bf16*  Rpad  = (bf16*)ttake(128ull * 512 * 2);
  float* RW1   = (float*)ttake(128ull * 1024 * 4);
  bf16*  ApadC = (bf16*)ttake(1280ull * 512 * 2);
  bf16*  PW1C  = (bf16*)ttake(1280ull * 1024 * 2);
  bf16*  H1C   = (bf16*)ttake(2560ull * 1024 * 2);

  T(proj_W1,               W1topT, 512, 1024);      // W1 rows 0..511   (e half)
  T(proj_W1 + 512ull*1024, W1botT, 512, 1024);      // W1 rows 512..1023 (r half)
  T(proj_W2, Wp2T, 1024, 512);
  pad_remb<<<128, 128, 0, stream>>>(remb, Rpad);
  gemm128<false, true, false, false><<<dim3(8, 1), 256, 0, stream>>>(Rpad, W1botT, proj_b1, nullptr, RW1, 128, 1024, 512);
  for (int pc = 0; pc < 4; ++pc) {                  // 1280 players / chunk
    pad_pemb<<<1280, 128, 0, stream>>>(pemb, ApadC, pc * 1280);
    gemm128<false, false, false, true ><<<dim3(8, 10), 256, 0, stream>>>(ApadC, W1topT, nullptr, nullptr, PW1C, 1280, 1024, 512);
    h1tab_kernel<<<2560, 256, 0, stream>>>(PW1C, RW1, H1C);
    gemm128<false, true,  false, true ><<<dim3(4, 20), 256, 0, stream>>>(H1C, Wp2T, proj_b2, nullptr, Z0tab + (size_t)pc * 2560 * 512, 2560, 512, 1024);
  }
  z0_gather<<<81920, 128, 0, stream>>>(off_ids, def_ids, off_pos, def_pos, Z0tab, Z, cbuf);

  // ---- transformer layers (JIT weight transposes; arena reused for activations)
  const int NCA = 81920 / McA, NCF = 81920 / McF;
  for (int l = 0; l < 4; ++l) {
    T(Wq + (size_t)l * 262144, WqkvT_l,          512, 512);
    T(Wk + (size_t)l * 262144, WqkvT_l + 262144, 512, 512);
    T(Wv + (size_t)l * 262144, WqkvT_l + 524288, 512, 512);
    T(Wo + (size_t)l * 262144, WoT_l,            512, 512);
    T(ffn_W1 + (size_t)l * 1048576, Wf1T_l, 512, 2048);
    T(ffn_W2 + (size_t)l * 1048576, Wf2T_l, 2048, 512);

    for (int c = 0; c < NCA; ++c) {                 // attention sub-block (4KB/row)
      const int r0 = c * McA;
      float* Zc = Z + (size_t)r0 * 512;
      bf16* Z1c  = (bf16*)arena;                    // McA x 512 (Z1, later reused as O)
      bf16* QKVc = (bf16*)(arena + (size_t)McA * 1024); // McA x 1536
      ln_kernel<<<McA/4, 256, 0, stream>>>(Zc, ln1_g + l*512, ln1_b + l*512, Z1c);
      gemm128<false, false, false, true ><<<dim3(12, McA/128), 256, 0, stream>>>(Z1c, WqkvT_l, nullptr, nullptr, QKVc, McA, 1536, 512);
      attn_kernel<<<McA/5, 256, 0, stream>>>(QKVc, cbuf + r0, bias_B + (size_t)l * 800, Z1c); // O overwrites Z1 (dead)
      gemm128<false, false, true,  false><<<dim3(4, McA/128),  256, 0, stream>>>(Z1c, WoT_l, nullptr, Zc, Zc, McA, 512, 512);
    }
    for (int c = 0; c < NCF; ++c) {                 // FFN sub-block (5KB/row)
      const int r0 = c * McF;
      float* Zc = Z + (size_t)r0 * 512;
      bf16* Z2c = (bf16*)arena;                     // McF x 512
      bf16* Hc  = (bf16*)(arena + (size_t)McF * 1024); // McF x 2048
      ln_kernel<<<McF/4, 256, 0, stream>>>(Zc, ln2_g + l*512, ln2_b + l*512, Z2c);
      gemm128<true,  true,  false, true ><<<dim3(16, McF/128), 256, 0, stream>>>(Z2c, Wf1T_l, ffn_b1 + (size_t)l * 2048, nullptr, Hc, McF, 2048, 512);
      gemm128<false, true,  true,  false><<<dim3(4, McF/128),  256, 0, stream>>>(Hc, Wf2T_l, ffn_b2 + (size_t)l * 512, Zc, Zc, McF, 512, 2048);
    }
  }

  // ---- head (zmean/hh overlay arena; head_W1 re-transposed into WJ)
  bf16* zmean = (bf16*)arena;                       // 8192 x 512 bf16
  bf16* hh    = (bf16*)(arena + 8388608ull);        // 8192 x 512 bf16
  bf16* Wh1T  = WJ;                                 // 512 x 512
  T(head_W1, Wh1T, 512, 512);
  mean_kernel<<<4096, 256, 0, stream>>>(Z, zmean);
  gemm128<true, true, false, true><<<dim3(4, 64), 256, 0, stream>>>(zmean, Wh1T, head_b1, nullptr, hh, 8192, 512, 512);
  head2_kernel<<<2048, 256, 0, stream>>>(hh, head_W2, head_b2, (float*)d_out);
}

// Round 12
// 3951.233 us; speedup vs baseline: 2.0066x; 1.1306x over previous
//
#include <hip/hip_runtime.h>
#include <hip/hip_bf16.h>
#include <stdint.h>

typedef __hip_bfloat16 bf16;
typedef __attribute__((ext_vector_type(4))) float f32x4;
typedef __attribute__((ext_vector_type(8))) short short8v;
typedef __attribute__((ext_vector_type(4))) short short4v;

union U8 { short8v v; bf16 h[8]; };
union U4 { short4v v; bf16 h[4]; };

#define DEV static __device__ __forceinline__

DEV bf16 f2bf(float f) { return __float2bfloat16(f); }
DEV float bf2f(bf16 h) { return __bfloat162float(h); }

DEV void async_copy16(bf16* lds, const bf16* g) {
  __builtin_amdgcn_global_load_lds(
      (const __attribute__((address_space(1))) unsigned int*)g,
      (__attribute__((address_space(3))) unsigned int*)lds,
      16, 0, 0);
}

// ---------------------------------------------------------------- GEMM 128x128
// C(M,N) = act( A(M,K)bf16 @ BT(N,K)^T + bias + Cin(bf16) ), 4 waves, BK=32.
// Double-buffer 2-phase + T1 bijective XCD-chunked swizzle (verified r11:
// qkv FETCH 86.5->27.3MB). ADDC accumulates in f32, Cin/Dout storage bf16.
template<bool RELU, bool BIAS, bool ADDC, bool OBF16>
__global__ __launch_bounds__(256)
void gemm128(const bf16* __restrict__ A, const bf16* __restrict__ BT,
             const float* __restrict__ bias, const bf16* __restrict__ Cin,
             void* __restrict__ Dout, int M, int N, int K)
{
  __shared__ __align__(16) bf16 lds[16384];   // 2 bufs x (A 4096 + B 4096 elems)
  const int tid = threadIdx.x;

  // T1: bid -> swz (m204 bijective chunked form)
  const int nwg = gridDim.x * gridDim.y;
  const int bid = blockIdx.y * gridDim.x + blockIdx.x;
  const int q = nwg >> 3, rr8 = nwg & 7;
  const int xcd = bid & 7, idx = bid >> 3;
  const int swz = (xcd < rr8 ? xcd * (q + 1) : rr8 * (q + 1) + (xcd - rr8) * q) + idx;
  const int m0 = (swz / gridDim.x) * 128;
  const int n0 = (swz % gridDim.x) * 128;

  const int wid = tid >> 6, lane = tid & 63;
  const int wr = wid >> 1, wc = wid & 1;
  const int r = lane & 15, g = lane >> 4;

  const int srow = tid >> 2;                   // 0..63
  const int scol = (tid & 3) * 8;
  const bf16* a0 = A  + (size_t)(m0 + srow) * K + scol;
  const bf16* a1 = A  + (size_t)(m0 + srow + 64) * K + scol;
  const bf16* b0 = BT + (size_t)(n0 + srow) * K + scol;
  const bf16* b1 = BT + (size_t)(n0 + srow + 64) * K + scol;

  const int NT = K >> 5;

  f32x4 acc[4][4];
  #pragma unroll
  for (int i = 0; i < 4; ++i)
    #pragma unroll
    for (int j = 0; j < 4; ++j) acc[i][j] = (f32x4){0.f, 0.f, 0.f, 0.f};

  auto STAGE = [&](int t, int buf) {           // 4 x 16B per thread
    bf16* dst = &lds[buf * 8192];
    const int kt = t << 5;
    async_copy16(dst +         tid * 8, a0 + kt);
    async_copy16(dst + 2048 +  tid * 8, a1 + kt);
    async_copy16(dst + 4096 +  tid * 8, b0 + kt);
    async_copy16(dst + 6144 +  tid * 8, b1 + kt);
  };

  STAGE(0, 0);
  __syncthreads();
  int cur = 0;
  for (int t = 0; t < NT; ++t) {
    if (t + 1 < NT) STAGE(t + 1, cur ^ 1);     // in flight during compute below

    const bf16* Ab = &lds[cur * 8192];
    const bf16* Bb = Ab + 4096;
    short8v af[4], bfr[4];
    #pragma unroll
    for (int mi = 0; mi < 4; ++mi)
      af[mi] = *(const short8v*)&Ab[(wr*64 + mi*16 + r) * 32 + g*8];
    #pragma unroll
    for (int ni = 0; ni < 4; ++ni)
      bfr[ni] = *(const short8v*)&Bb[(wc*64 + ni*16 + r) * 32 + g*8];

    __builtin_amdgcn_s_setprio(1);
    #pragma unroll
    for (int mi = 0; mi < 4; ++mi)
      #pragma unroll
      for (int ni = 0; ni < 4; ++ni)
        acc[mi][ni] = __builtin_amdgcn_mfma_f32_16x16x32_bf16(af[mi], bfr[ni], acc[mi][ni], 0, 0, 0);
    __builtin_amdgcn_s_setprio(0);

    __syncthreads();                           // next tile landed; reads done
    cur ^= 1;
  }

  const int mbase = m0 + wr*64;
  const int nbase = n0 + wc*64;
  #pragma unroll
  for (int ni = 0; ni < 4; ++ni) {
    const int col = nbase + ni*16 + r;
    const float bv = BIAS ? bias[col] : 0.f;
    #pragma unroll
    for (int mi = 0; mi < 4; ++mi) {
      #pragma unroll
      for (int b4 = 0; b4 < 4; ++b4) {
        const int row = mbase + mi*16 + g*4 + b4;
        float v = acc[mi][ni][b4] + bv;
        if (ADDC) v += bf2f(Cin[(size_t)row * N + col]);   // f32 accumulate
        if (RELU) v = fmaxf(v, 0.f);
        if (OBF16) ((bf16*)Dout)[(size_t)row * N + col] = f2bf(v);
        else       ((float*)Dout)[(size_t)row * N + col] = v;
      }
    }
  }
}

// ---------------------------------------------------------------- weights: W(K,N) f32 -> WT(N,K) bf16
__global__ __launch_bounds__(256)
void transpose_w(const float* __restrict__ W, bf16* __restrict__ WT, int K, int N)
{
  __shared__ float tl[32][33];
  const int n0 = blockIdx.x * 32, k0 = blockIdx.y * 32;
  const int r = threadIdx.x >> 5, c = threadIdx.x & 31;
  #pragma unroll
  for (int rr = r; rr < 32; rr += 8) tl[rr][c] = W[(size_t)(k0 + rr) * N + n0 + c];
  __syncthreads();
  #pragma unroll
  for (int rr = r; rr < 32; rr += 8) WT[(size_t)(n0 + rr) * K + k0 + c] = f2bf(tl[c][rr]);
}

// ---------------------------------------------------------------- pad pemb chunk: rows [p0, p0+1280)
__global__ __launch_bounds__(128)
void pad_pemb(const float* __restrict__ pemb, bf16* __restrict__ Apad, int p0)
{
  const int lrow = blockIdx.x;
  const int grow = p0 + lrow;
  const int c = threadIdx.x * 4;
  U4 u;
  if (grow < 5000) {
    f32x4 v = *(const f32x4*)(pemb + (size_t)grow * 512 + c);
    u.h[0]=f2bf(v[0]); u.h[1]=f2bf(v[1]); u.h[2]=f2bf(v[2]); u.h[3]=f2bf(v[3]);
  } else {
    u.v = (short4v){0,0,0,0};
  }
  *(short4v*)(Apad + (size_t)lrow * 512 + c) = u.v;
}

// ---------------------------------------------------------------- pad remb -> Rpad (128x512 bf16)
__global__ __launch_bounds__(128)
void pad_remb(const float* __restrict__ remb, bf16* __restrict__ Rpad)
{
  const int row = blockIdx.x;
  const int c = threadIdx.x * 4;
  U4 u;
  if (row < 2) {
    f32x4 v = *(const f32x4*)(remb + (size_t)row * 512 + c);
    u.h[0]=f2bf(v[0]); u.h[1]=f2bf(v[1]); u.h[2]=f2bf(v[2]); u.h[3]=f2bf(v[3]);
  } else {
    u.v = (short4v){0,0,0,0};
  }
  *(short4v*)(Rpad + (size_t)row * 512 + c) = u.v;
}

// ---------------------------------------------------------------- H1 chunk: relu(PW1_c[p] + RW1[role])
__global__ __launch_bounds__(256)
void h1tab_kernel(const bf16* __restrict__ PW1c, const float* __restrict__ RW1,
                  bf16* __restrict__ H1c)
{
  const int row = blockIdx.x;            // 0..2559 : p_local*2+role
  const int p = row >> 1, role = row & 1;
  const int c = threadIdx.x * 4;
  U4 a; a.v = *(const short4v*)(PW1c + (size_t)p * 1024 + c);
  f32x4 rv = *(const f32x4*)(RW1 + (size_t)role * 1024 + c);
  U4 o;
  #pragma unroll
  for (int j = 0; j < 4; ++j) o.h[j] = f2bf(fmaxf(bf2f(a.h[j]) + rv[j], 0.f));
  *(short4v*)(H1c + (size_t)row * 1024 + c) = o.v;
}

// ---------------------------------------------------------------- Z0 gather: Z[row] = Z0tab[pid*2+role] (bf16 copy); cbuf
__global__ __launch_bounds__(128)
void z0_gather(const int* __restrict__ off_ids, const int* __restrict__ def_ids,
               const int* __restrict__ off_pos, const int* __restrict__ def_pos,
               const bf16* __restrict__ Z0tab, bf16* __restrict__ Z,
               int* __restrict__ cbuf)
{
  const int row = blockIdx.x;            // 0..81919
  const int b = row / 10, t = row % 10;
  int pid, pos, role;
  if (t < 5) { pid = off_ids[b*5 + t];   pos = off_pos[b*5 + t];   role = 0; }
  else       { pid = def_ids[b*5 + t-5]; pos = def_pos[b*5 + t-5]; role = 1; }
  if (threadIdx.x == 0) cbuf[row] = role * 5 + pos;
  const int c = threadIdx.x * 4;
  *(short4v*)(Z + (size_t)row * 512 + c) =
      *(const short4v*)(Z0tab + (size_t)(pid * 2 + role) * 512 + c);
}

// ---------------------------------------------------------------- LayerNorm rows of 512, bf16 in -> bf16 out (f32 stats)
__global__ __launch_bounds__(256)
void ln_kernel(const bf16* __restrict__ Zin, const float* __restrict__ gam,
               const float* __restrict__ bet, bf16* __restrict__ outp)
{
  const int w = threadIdx.x >> 6, lane = threadIdx.x & 63;
  const size_t row = (size_t)blockIdx.x * 4 + w;
  U8 u; u.v = *(const short8v*)(Zin + row * 512 + lane * 8);
  float x[8];
  float s = 0.f, ss = 0.f;
  #pragma unroll
  for (int j = 0; j < 8; ++j) { x[j] = bf2f(u.h[j]); s += x[j]; ss += x[j]*x[j]; }
  for (int d0 = 1; d0 < 64; d0 <<= 1) { s += __shfl_xor(s, d0); ss += __shfl_xor(ss, d0); }
  const float mu = s * (1.f/512.f);
  const float rstd = rsqrtf(ss * (1.f/512.f) - mu*mu + 1e-5f);
  const float* gp = gam + lane * 8;
  const float* bp = bet + lane * 8;
  f32x4 g0 = *(const f32x4*)gp, g1 = *(const f32x4*)(gp + 4);
  f32x4 b0 = *(const f32x4*)bp, b1 = *(const f32x4*)(bp + 4);
  U8 o;
  #pragma unroll
  for (int j = 0; j < 4; ++j) o.h[j]     = f2bf((x[j]  -mu)*rstd*g0[j] + b0[j]);
  #pragma unroll
  for (int j = 0; j < 4; ++j) o.h[4 + j] = f2bf((x[4+j]-mu)*rstd*g1[j] + b1[j]);
  *(short8v*)(outp + row * 512 + lane * 8) = o.v;
}

// ---------------------------------------------------------------- attention: one wave per (local b, h)
__global__ __launch_bounds__(256)
void attn_kernel(const bf16* __restrict__ qkv, const int* __restrict__ cbuf,
                 const float* __restrict__ biasL, bf16* __restrict__ O)
{
  __shared__ __align__(16) bf16 Plds[4][256];
  __shared__ __align__(16) bf16 Vt[4][1024];
  const int w = threadIdx.x >> 6, lane = threadIdx.x & 63;
  const int wv = blockIdx.x * 4 + w;
  const int b = wv >> 3, h = wv & 7;
  const int r = lane & 15, g = lane >> 4;
  const bf16* base = qkv + (size_t)b * 15360;
  const bool rv = r < 10;
  const short8v z8 = {0,0,0,0,0,0,0,0};

  short8v aq0 = z8, aq1 = z8, bk0 = z8, bk1 = z8;
  if (rv) {
    const bf16* qp = base + (size_t)r * 1536 + h * 64 + g * 8;
    aq0 = *(const short8v*)qp;
    aq1 = *(const short8v*)(qp + 32);
    bk0 = *(const short8v*)(qp + 512);
    bk1 = *(const short8v*)(qp + 544);
  }
  f32x4 s = {0.f, 0.f, 0.f, 0.f};
  s = __builtin_amdgcn_mfma_f32_16x16x32_bf16(aq0, bk0, s, 0, 0, 0);
  s = __builtin_amdgcn_mfma_f32_16x16x32_bf16(aq1, bk1, s, 0, 0, 0);

  bf16* V = Vt[w];
  {
    const int j1 = lane >> 3, d0 = (lane & 7) * 8;
    U8 uv; uv.v = *(const short8v*)(base + (size_t)j1 * 1536 + 1024 + h * 64 + d0);
    #pragma unroll
    for (int m2 = 0; m2 < 8; ++m2) V[(d0 + m2) * 16 + j1] = uv.h[m2];
    const int j2 = 8 + j1;
    U8 uv2; uv2.v = z8;
    if (j2 < 10) uv2.v = *(const short8v*)(base + (size_t)j2 * 1536 + 1024 + h * 64 + d0);
    #pragma unroll
    for (int m2 = 0; m2 < 8; ++m2) V[(d0 + m2) * 16 + j2] = uv2.h[m2];
  }

  const int cj = rv ? cbuf[b * 10 + r] : 0;
  float sv[4];
  #pragma unroll
  for (int q4 = 0; q4 < 4; ++q4) {
    const int i = g * 4 + q4;
    float val = s[q4] * 0.125f;
    if (rv && i < 10) val += biasL[h * 100 + cbuf[b * 10 + i] * 10 + cj];
    if (!rv) val = -1e30f;
    sv[q4] = val;
  }
  float mx[4];
  #pragma unroll
  for (int q4 = 0; q4 < 4; ++q4) mx[q4] = sv[q4];
  for (int d0 = 1; d0 < 16; d0 <<= 1) {
    #pragma unroll
    for (int q4 = 0; q4 < 4; ++q4) mx[q4] = fmaxf(mx[q4], __shfl_xor(mx[q4], d0));
  }
  float pe[4], sm[4];
  #pragma unroll
  for (int q4 = 0; q4 < 4; ++q4) { pe[q4] = __expf(sv[q4] - mx[q4]); sm[q4] = pe[q4]; }
  for (int d0 = 1; d0 < 16; d0 <<= 1) {
    #pragma unroll
    for (int q4 = 0; q4 < 4; ++q4) sm[q4] += __shfl_xor(sm[q4], d0);
  }

  bf16* P = Plds[w];
  #pragma unroll
  for (int q4 = 0; q4 < 4; ++q4) P[(g * 4 + q4) * 16 + r] = f2bf(pe[q4] / sm[q4]);

  short8v pa = z8;
  if (g < 2) pa = *(const short8v*)&P[r * 16 + g * 8];
  #pragma unroll
  for (int db = 0; db < 4; ++db) {
    short8v bv = z8;
    if (g < 2) bv = *(const short8v*)&V[(db * 16 + r) * 16 + g * 8];
    f32x4 o = {0.f, 0.f, 0.f, 0.f};
    o = __builtin_amdgcn_mfma_f32_16x16x32_bf16(pa, bv, o, 0, 0, 0);
    #pragma unroll
    for (int q4 = 0; q4 < 4; ++q4) {
      const int i = g * 4 + q4;
      if (i < 10) O[(size_t)(b * 10 + i) * 512 + h * 64 + db * 16 + r] = f2bf(o[q4]);
    }
  }
}

// ---------------------------------------------------------------- token mean: bf16 Z -> bf16 zmean (f32 accum)
__global__ __launch_bounds__(256)
void mean_kernel(const bf16* __restrict__ Zin, bf16* __restrict__ zm)
{
  const int idx = blockIdx.x * 256 + threadIdx.x;
  const int b = idx >> 7, d4 = (idx & 127) << 2;
  const bf16* p = Zin + (size_t)b * 5120 + d4;
  f32x4 a = {0.f, 0.f, 0.f, 0.f};
  #pragma unroll
  for (int i = 0; i < 10; ++i) {
    U4 u; u.v = *(const short4v*)(p + (size_t)i * 512);
    #pragma unroll
    for (int j = 0; j < 4; ++j) a[j] += bf2f(u.h[j]);
  }
  a *= 0.1f;
  U4 u;
  #pragma unroll
  for (int j = 0; j < 4; ++j) u.h[j] = f2bf(a[j]);
  *(short4v*)(zm + (size_t)b * 512 + d4) = u.v;
}

// ---------------------------------------------------------------- head2
__global__ __launch_bounds__(256)
void head2_kernel(const bf16* __restrict__ hh, const float* __restrict__ W2,
                  const float* __restrict__ b2, float* __restrict__ out)
{
  const int w = threadIdx.x >> 6, lane = threadIdx.x & 63;
  const int b = blockIdx.x * 4 + w;
  U8 u; u.v = *(const short8v*)(hh + (size_t)b * 512 + lane * 8);
  float p[5] = {0.f, 0.f, 0.f, 0.f, 0.f};
  #pragma unroll
  for (int j = 0; j < 8; ++j) {
    const float hf = bf2f(u.h[j]);
    const float* wp = W2 + (size_t)(lane * 8 + j) * 5;
    #pragma unroll
    for (int c = 0; c < 5; ++c) p[c] += hf * wp[c];
  }
  for (int d0 = 1; d0 < 64; d0 <<= 1) {
    #pragma unroll
    for (int c = 0; c < 5; ++c) p[c] += __shfl_xor(p[c], d0);
  }
  if (lane == 0) {
    float* op = out + (size_t)b * 5;
    #pragma unroll
    for (int c = 0; c < 5; ++c) op[c] = p[c] + b2[c];
  }
}

// ----------------------------------------------------------------
extern "C" void kernel_launch(void* const* d_in, const int* in_sizes, int n_in,
                              void* d_out, int out_size, void* d_ws, size_t ws_size,
                              hipStream_t stream)
{
  const int*   off_ids = (const int*)d_in[0];
  const int*   def_ids = (const int*)d_in[1];
  const int*   off_pos = (const int*)d_in[2];
  const int*   def_pos = (const int*)d_in[3];
  const float* pemb    = (const float*)d_in[4];
  const float* remb    = (const float*)d_in[5];
  const float* proj_W1 = (const float*)d_in[6];
  const float* proj_b1 = (const float*)d_in[7];
  const float* proj_W2 = (const float*)d_in[8];
  const float* proj_b2 = (const float*)d_in[9];
  const float* ln1_g   = (const float*)d_in[10];
  const float* ln1_b   = (const float*)d_in[11];
  const float* Wq      = (const float*)d_in[12];
  const float* Wk      = (const float*)d_in[13];
  const float* Wv      = (const float*)d_in[14];
  const float* Wo      = (const float*)d_in[15];
  const float* bias_B  = (const float*)d_in[16];
  const float* ln2_g   = (const float*)d_in[17];
  const float* ln2_b   = (const float*)d_in[18];
  const float* ffn_W1  = (const float*)d_in[19];
  const float* ffn_b1  = (const float*)d_in[20];
  const float* ffn_W2  = (const float*)d_in[21];
  const float* ffn_b2  = (const float*)d_in[22];
  const float* head_W1 = (const float*)d_in[23];
  const float* head_b1 = (const float*)d_in[24];
  const float* head_W2 = (const float*)d_in[25];
  const float* head_b2 = (const float*)d_in[26];
  (void)in_sizes; (void)n_in; (void)out_size;

  char* ws = (char*)d_ws;
  size_t off = 0;
  auto take = [&](size_t bytes) -> char* {
    char* p = ws + off; off += (bytes + 255) & ~(size_t)255; return p;
  };

  // ---- fixed allocations (~86.6 MiB)
  bf16*  Z    = (bf16*)take(81920ull * 512 * 2);    // residual bf16 (80MiB)
  bf16*  WJ   = (bf16*)take(3145728ull * 2);        // 6MiB per-layer weight buffer (JIT)
  int*   cbuf = (int*)take(81920ull * 4);

  // ---- adaptive chunk sizes
  const size_t fixed_end = off;
  const size_t avail = (ws_size > fixed_end + (1u << 20)) ? (ws_size - fixed_end - (1u << 20)) : 0;
  int McA = 81920;                                   // attn phase: 4KB/row (Z1|O + QKV)
  while (McA > 2560 && (size_t)McA * 4096 > avail) McA >>= 1;
  int McF = 81920;                                   // ffn phase: 5KB/row (Z2 + H)
  while (McF > 2560 && (size_t)McF * 5120 > avail) McF >>= 1;
  char* arena = ws + fixed_end;

  // per-layer weight views inside WJ (elems)
  bf16* WqkvT_l = WJ;                 // 1536 x 512
  bf16* WoT_l   = WJ +  786432;       //  512 x 512
  bf16* Wf1T_l  = WJ + 1048576;       // 2048 x 512
  bf16* Wf2T_l  = WJ + 2097152;       //  512 x 2048

  auto T = [&](const float* W, bf16* WT, int K, int N) {
    transpose_w<<<dim3(N / 32, K / 32), 256, 0, stream>>>(W, WT, K, N);
  };

  // ---- prologue: Z0tab[(pid,role)] replaces the proj MLP on all 81920 rows
  bf16* W1topT = WJ;                  // 1024 x 512
  bf16* W1botT = WJ +  524288;        // 1024 x 512
  bf16* Wp2T   = WJ + 1048576;        //  512 x 1024
  char* tb = arena;
  auto ttake = [&](size_t bytes) -> char* {
    char* p = tb; tb += (bytes + 255) & ~(size_t)255; return p;
  };
  bf16*  Z0tab = (bf16*)ttake(10240ull * 512 * 2);  // 10MiB
  bf16*  Rpad  = (bf16*)ttake(128ull * 512 * 2);
  float* RW1   = (float*)ttake(128ull * 1024 * 4);
  bf16*  ApadC = (bf16*)ttake(1280ull * 512 * 2);
  bf16*  PW1C  = (bf16*)ttake(1280ull * 1024 * 2);
  bf16*  H1C   = (bf16*)ttake(2560ull * 1024 * 2);

  T(proj_W1,               W1topT, 512, 1024);      // W1 rows 0..511   (e half)
  T(proj_W1 + 512ull*1024, W1botT, 512, 1024);      // W1 rows 512..1023 (r half)
  T(proj_W2, Wp2T, 1024, 512);
  pad_remb<<<128, 128, 0, stream>>>(remb, Rpad);
  gemm128<false, true, false, false><<<dim3(8, 1), 256, 0, stream>>>(Rpad, W1botT, proj_b1, nullptr, RW1, 128, 1024, 512);
  for (int pc = 0; pc < 4; ++pc) {                  // 1280 players / chunk
    pad_pemb<<<1280, 128, 0, stream>>>(pemb, ApadC, pc * 1280);
    gemm128<false, false, false, true ><<<dim3(8, 10), 256, 0, stream>>>(ApadC, W1topT, nullptr, nullptr, PW1C, 1280, 1024, 512);
    h1tab_kernel<<<2560, 256, 0, stream>>>(PW1C, RW1, H1C);
    gemm128<false, true,  false, true ><<<dim3(4, 20), 256, 0, stream>>>(H1C, Wp2T, proj_b2, nullptr, Z0tab + (size_t)pc * 2560 * 512, 2560, 512, 1024);
  }
  z0_gather<<<81920, 128, 0, stream>>>(off_ids, def_ids, off_pos, def_pos, Z0tab, Z, cbuf);

  // ---- transformer layers (JIT weight transposes; arena reused for activations)
  const int NCA = 81920 / McA, NCF = 81920 / McF;
  for (int l = 0; l < 4; ++l) {
    T(Wq + (size_t)l * 262144, WqkvT_l,          512, 512);
    T(Wk + (size_t)l * 262144, WqkvT_l + 262144, 512, 512);
    T(Wv + (size_t)l * 262144, WqkvT_l + 524288, 512, 512);
    T(Wo + (size_t)l * 262144, WoT_l,            512, 512);
    T(ffn_W1 + (size_t)l * 1048576, Wf1T_l, 512, 2048);
    T(ffn_W2 + (size_t)l * 1048576, Wf2T_l, 2048, 512);

    for (int c = 0; c < NCA; ++c) {                 // attention sub-block (4KB/row)
      const int r0 = c * McA;
      bf16* Zc = Z + (size_t)r0 * 512;
      bf16* Z1c  = (bf16*)arena;                    // McA x 512 (Z1, later reused as O)
      bf16* QKVc = (bf16*)(arena + (size_t)McA * 1024); // McA x 1536
      ln_kernel<<<McA/4, 256, 0, stream>>>(Zc, ln1_g + l*512, ln1_b + l*512, Z1c);
      gemm128<false, false, false, true ><<<dim3(12, McA/128), 256, 0, stream>>>(Z1c, WqkvT_l, nullptr, nullptr, QKVc, McA, 1536, 512);
      attn_kernel<<<McA/5, 256, 0, stream>>>(QKVc, cbuf + r0, bias_B + (size_t)l * 800, Z1c); // O overwrites Z1 (dead)
      gemm128<false, false, true,  true ><<<dim3(4, McA/128),  256, 0, stream>>>(Z1c, WoT_l, nullptr, Zc, Zc, McA, 512, 512);
    }
    for (int c = 0; c < NCF; ++c) {                 // FFN sub-block (5KB/row)
      const int r0 = c * McF;
      bf16* Zc = Z + (size_t)r0 * 512;
      bf16* Z2c = (bf16*)arena;                     // McF x 512
      bf16* Hc  = (bf16*)(arena + (size_t)McF * 1024); // McF x 2048
      ln_kernel<<<McF/4, 256, 0, stream>>>(Zc, ln2_g + l*512, ln2_b + l*512, Z2c);
      gemm128<true,  true,  false, true ><<<dim3(16, McF/128), 256, 0, stream>>>(Z2c, Wf1T_l, ffn_b1 + (size_t)l * 2048, nullptr, Hc, McF, 2048, 512);
      gemm128<false, true,  true,  true ><<<dim3(4, McF/128),  256, 0, stream>>>(Hc, Wf2T_l, ffn_b2 + (size_t)l * 512, Zc, Zc, McF, 512, 2048);
    }
  }

  // ---- head (zmean/hh overlay arena; head_W1 re-transposed into WJ)
  bf16* zmean = (bf16*)arena;                       // 8192 x 512 bf16
  bf16* hh    = (bf16*)(arena + 8388608ull);        // 8192 x 512 bf16
  bf16* Wh1T  = WJ;                                 // 512 x 512
  T(head_W1, Wh1T, 512, 512);
  mean_kernel<<<4096, 256, 0, stream>>>(Z, zmean);
  gemm128<true, true, false, true><<<dim3(4, 64), 256, 0, stream>>>(zmean, Wh1T, head_b1, nullptr, hh, 8192, 512, 512);
  head2_kernel<<<2048, 256, 0, stream>>>(hh, head_W2, head_b2, (float*)d_out);
}